// Round 10
// baseline (822.675 us; speedup 1.0000x reference)
//
#include <hip/hip_runtime.h>

#define NN 50000
#define NE 1000000

constexpr float LN_EPS = 1e-5f;

typedef short bf16x8 __attribute__((ext_vector_type(8)));
typedef float f32x4 __attribute__((ext_vector_type(4)));
typedef uint uvec4 __attribute__((ext_vector_type(4)));
typedef uint uvec2 __attribute__((ext_vector_type(2)));

// round-to-nearest-even float -> bf16
__device__ inline ushort f2bf(float x) {
  union { float f; uint u; } v; v.f = x;
  uint r = v.u + 0x7fffu + ((v.u >> 16) & 1u);
  return (ushort)(r >> 16);
}
__device__ inline uint pkbf(float a, float b) {
  union { float f; uint u; } x, y; x.f = a; y.f = b;
  uint ra = (x.u + 0x7fffu + ((x.u >> 16) & 1u)) >> 16;
  uint rb = (y.u + 0x7fffu + ((y.u >> 16) & 1u)) & 0xffff0000u;
  return ra | rb;
}
__device__ inline float bflo(uint u) { union { uint x; float f; } v; v.x = u << 16; return v.f; }
__device__ inline float bfhi(uint u) { union { uint x; float f; } v; v.x = u & 0xffff0000u; return v.f; }
__device__ inline void ea8(uvec4 E, float* o) {
  o[0] = bflo(E.x); o[1] = bfhi(E.x); o[2] = bflo(E.y); o[3] = bfhi(E.y);
  o[4] = bflo(E.z); o[5] = bfhi(E.z); o[6] = bflo(E.w); o[7] = bfhi(E.w);
}

// ---------------------------------------------------------------------------
// CSR build: histogram -> exclusive scan -> scatter.
__global__ __launch_bounds__(256) void hist_kernel(const int* __restrict__ ei,
                                                   int* __restrict__ cnt) {
  int e = blockIdx.x * 256 + threadIdx.x;
  if (e < NE) atomicAdd(&cnt[ei[NE + e]], 1);
}

__global__ __launch_bounds__(256) void scan1_kernel(const int* __restrict__ cnt,
                                                    int* __restrict__ off,
                                                    int* __restrict__ bsum) {
  __shared__ int sh[256];
  int t = threadIdx.x;
  int idx = blockIdx.x * 256 + t;
  int v = (idx < NN) ? cnt[idx] : 0;
  sh[t] = v;
  __syncthreads();
  for (int o = 1; o < 256; o <<= 1) {
    int xv = (t >= o) ? sh[t - o] : 0;
    __syncthreads();
    sh[t] += xv;
    __syncthreads();
  }
  if (idx <= NN) off[idx] = sh[t] - v;
  if (t == 255) bsum[blockIdx.x] = sh[255];
}

__global__ __launch_bounds__(256) void scan2_kernel(int* __restrict__ bsum, int nb) {
  __shared__ int sh[256];
  int t = threadIdx.x;
  int v = (t < nb) ? bsum[t] : 0;
  sh[t] = v;
  __syncthreads();
  for (int o = 1; o < 256; o <<= 1) {
    int xv = (t >= o) ? sh[t - o] : 0;
    __syncthreads();
    sh[t] += xv;
    __syncthreads();
  }
  if (t < nb) bsum[t] = sh[t] - v;
}

__global__ __launch_bounds__(256) void scan3_kernel(int* __restrict__ off,
                                                    const int* __restrict__ bsum,
                                                    int* __restrict__ cnt) {
  int idx = blockIdx.x * 256 + threadIdx.x;
  if (idx <= NN) off[idx] += bsum[blockIdx.x];
  if (idx < NN) cnt[idx] = 0;
}

// scatter emits: srcp/dstp (sorted endpoint ids), eapb (dst-sorted bf16 edge
// attrs), ipos (edge -> sorted position inverse map, coalesced by e).
__global__ __launch_bounds__(256) void scatter_kernel(
    const int* __restrict__ ei, const float* __restrict__ ea,
    const int* __restrict__ off, int* __restrict__ cur,
    int* __restrict__ ipos, int* __restrict__ srcp, int* __restrict__ dstp,
    ushort* __restrict__ eapb) {
  int e = blockIdx.x * 256 + threadIdx.x;
  if (e < NE) {
    int d = ei[NE + e];
    int s = ei[e];
    int p = off[d] + atomicAdd(&cur[d], 1);
    ipos[e] = p;
    srcp[p] = s;
    dstp[p] = d;
    const float* eaf = ea + (size_t)e * 8;
    uvec4 u;
    u.x = pkbf(eaf[0], eaf[1]);
    u.y = pkbf(eaf[2], eaf[3]);
    u.z = pkbf(eaf[4], eaf[5]);
    u.w = pkbf(eaf[6], eaf[7]);
    __builtin_nontemporal_store(u, (uvec4*)(eapb + (size_t)p * 8));
  }
}

// unpermute: coalesced write of out, random 4B read of the 4MB tmp table.
__global__ __launch_bounds__(256) void unperm_kernel(const float* __restrict__ tmp,
                                                     const int* __restrict__ ipos,
                                                     float* __restrict__ out) {
  int e = blockIdx.x * 256 + threadIdx.x;
  if (e < NE) out[e] = tmp[ipos[e]];
}

// ---------------------------------------------------------------------------
__device__ inline float lane_layernorm(float r, float g, float b) {
  float s = r;
#pragma unroll
  for (int m = 32; m >= 1; m >>= 1) s += __shfl_xor(s, m);
  float mu = s * (1.f / 64.f);
  float dv = r - mu;
  float v = dv * dv;
#pragma unroll
  for (int m = 32; m >= 1; m >>= 1) v += __shfl_xor(v, m);
  float var = v * (1.f / 64.f);
  return dv * rsqrtf(var + LN_EPS) * g + b;
}

// ---------------------------------------------------------------------------
// Fused layer 0 (D=16): aggregation + MLP + residual Linear + LN.
__global__ __launch_bounds__(256) void layer0_fused(
    const float* __restrict__ x, float* __restrict__ hout,
    ushort* __restrict__ houtbf,
    const ushort* __restrict__ eapb, const int* __restrict__ srcp,
    const int* __restrict__ off,
    const float* __restrict__ lw, const float* __restrict__ lb,
    const float* __restrict__ w1, const float* __restrict__ b1,
    const float* __restrict__ w2, const float* __restrict__ b2,
    const float* __restrict__ lng, const float* __restrict__ lnb,
    const float* __restrict__ rw, const float* __restrict__ rb) {
  int n = blockIdx.x * 4 + (threadIdx.x >> 6);
  int j = threadIdx.x & 63;
  int d = j & 15, slot = j >> 4;
  int start = off[n], end = off[n + 1];
  float lwv[8];
#pragma unroll
  for (int i = 0; i < 8; i++) lwv[i] = lw[i * 16 + d];
  float lbv = lb[d];
  float acc = 0.f;
  for (int base = start; base < end; base += 64) {
    int idx = base + j;
    int sl = (idx < end) ? srcp[idx] : 0;
    int c = min(end - base, 64);
    for (int i0 = 0; i0 < c; i0 += 4) {
      int i = i0 + slot;
      bool valid = i < c;
      int ii = i & 63;
      int s = __shfl(sl, ii);
      int pp = min(base + i0 + slot, NE - 1);
      float ev = bflo((uint)eapb[(size_t)pp * 8 + (d & 7)]);
      float xs = x[(size_t)s * 16 + d];
      float m = lbv + xs;
#pragma unroll
      for (int q = 0; q < 8; q++) m = fmaf(__shfl(ev, slot * 16 + q), lwv[q], m);
      m = fmaxf(m, 0.f);
      acc += valid ? m : 0.f;
    }
  }
  acc += __shfl_xor(acc, 16);
  acc += __shfl_xor(acc, 32);
  float xr = x[(size_t)n * 16 + d];
  float t = xr + acc;
  float q1 = b1[j];
#pragma unroll 4
  for (int k = 0; k < 16; k++) q1 = fmaf(__shfl(t, k), w1[k * 64 + j], q1);
  q1 = fmaxf(q1, 0.f);
  float h2 = b2[j];
  for (int k = 0; k < 64; k++) h2 = fmaf(__shfl(q1, k), w2[k * 64 + j], h2);
  h2 = fmaxf(h2, 0.f);
  float res = rb[j];
#pragma unroll 4
  for (int k = 0; k < 16; k++) res = fmaf(__shfl(xr, k), rw[k * 64 + j], res);
  float v = lane_layernorm(h2 + res, lng[j], lnb[j]);
  hout[(size_t)n * 64 + j] = v;
  houtbf[(size_t)n * 64 + j] = f2bf(v);
}

// ---------------------------------------------------------------------------
// Fused layers 1/2 (D=64): bf16 h gathers; eapb/srcp/hinf consumed once ->
// nt loads so the hinb gather table stays L2-resident.
__global__ __launch_bounds__(256) void layer_fused(
    const ushort* __restrict__ hinb, const float* __restrict__ hinf,
    float* __restrict__ houtf, ushort* __restrict__ houtbf,
    const ushort* __restrict__ eapb, const int* __restrict__ srcp,
    const int* __restrict__ off,
    const float* __restrict__ lw, const float* __restrict__ lb,
    const float* __restrict__ w1, const float* __restrict__ b1,
    const float* __restrict__ w2, const float* __restrict__ b2,
    const float* __restrict__ lng, const float* __restrict__ lnb) {
  int n = blockIdx.x * 4 + (threadIdx.x >> 6);
  int j = threadIdx.x & 63;
  int start = off[n], end = off[n + 1];
  float lwv[8];
#pragma unroll
  for (int i = 0; i < 8; i++) lwv[i] = lw[i * 64 + j];
  float lbv = lb[j];
  float acc = 0.f;
  for (int base = start; base < end; base += 64) {
    int idx = base + j;
    int sl = (idx < end) ? __builtin_nontemporal_load(&srcp[idx]) : 0;
    int c = min(end - base, 64);
    int i = 0;
    for (; i + 4 <= c; i += 4) {
      int s0 = __builtin_amdgcn_readfirstlane(__shfl(sl, i));
      int s1 = __builtin_amdgcn_readfirstlane(__shfl(sl, i + 1));
      int s2 = __builtin_amdgcn_readfirstlane(__shfl(sl, i + 2));
      int s3 = __builtin_amdgcn_readfirstlane(__shfl(sl, i + 3));
      float h0 = bflo((uint)hinb[(size_t)s0 * 64 + j]);
      float h1 = bflo((uint)hinb[(size_t)s1 * 64 + j]);
      float h2v = bflo((uint)hinb[(size_t)s2 * 64 + j]);
      float h3 = bflo((uint)hinb[(size_t)s3 * 64 + j]);
      const uvec4* ep = (const uvec4*)(eapb + (size_t)(base + i) * 8);
      uvec4 E0 = __builtin_nontemporal_load(ep + 0);
      uvec4 E1 = __builtin_nontemporal_load(ep + 1);
      uvec4 E2 = __builtin_nontemporal_load(ep + 2);
      uvec4 E3 = __builtin_nontemporal_load(ep + 3);
      float a0[8], a1[8], a2[8], a3[8];
      ea8(E0, a0); ea8(E1, a1); ea8(E2, a2); ea8(E3, a3);
      float m0 = lbv + h0, m1 = lbv + h1, m2 = lbv + h2v, m3 = lbv + h3;
#pragma unroll
      for (int q = 0; q < 8; q++) {
        m0 = fmaf(a0[q], lwv[q], m0);
        m1 = fmaf(a1[q], lwv[q], m1);
        m2 = fmaf(a2[q], lwv[q], m2);
        m3 = fmaf(a3[q], lwv[q], m3);
      }
      acc += fmaxf(m0, 0.f) + fmaxf(m1, 0.f) + fmaxf(m2, 0.f) + fmaxf(m3, 0.f);
    }
    for (; i < c; i++) {
      int s = __builtin_amdgcn_readfirstlane(__shfl(sl, i));
      float hc = bflo((uint)hinb[(size_t)s * 64 + j]);
      uvec4 E = __builtin_nontemporal_load((const uvec4*)(eapb + (size_t)(base + i) * 8));
      float a[8];
      ea8(E, a);
      float m = lbv + hc;
#pragma unroll
      for (int q = 0; q < 8; q++) m = fmaf(a[q], lwv[q], m);
      acc += fmaxf(m, 0.f);
    }
  }
  float hv = __builtin_nontemporal_load(&hinf[(size_t)n * 64 + j]);
  float t = hv + acc;
  float q1 = b1[j];
  for (int k = 0; k < 64; k++) q1 = fmaf(__shfl(t, k), w1[k * 64 + j], q1);
  q1 = fmaxf(q1, 0.f);
  float h2 = b2[j];
  for (int k = 0; k < 64; k++) h2 = fmaf(__shfl(q1, k), w2[k * 64 + j], h2);
  h2 = fmaxf(h2, 0.f);
  float v = lane_layernorm(h2 + hv, lng[j], lnb[j]);
  if (houtf) houtf[(size_t)n * 64 + j] = v;
  houtbf[(size_t)n * 64 + j] = f2bf(v);
}

// ---------------------------------------------------------------------------
// Prep: dec_w1 (264x64, K zero-padded to 288) and dec_w2 (64x32) into per-lane
// bf16 B-fragments for mfma_f32_16x16x32_bf16.
__global__ __launch_bounds__(256) void prep_kernel(
    const float* __restrict__ w1, const float* __restrict__ w2,
    ushort* __restrict__ w1f, ushort* __restrict__ w2f) {
  int t = blockIdx.x * 256 + threadIdx.x;
  if (t < 18432) {
    int j = t & 7, lane = (t >> 3) & 63, f = t >> 9;
    int k = (f >> 2) * 32 + ((lane >> 4) * 8) + j;
    int n = (f & 3) * 16 + (lane & 15);
    float v = (k < 264) ? w1[k * 64 + n] : 0.f;
    w1f[t] = f2bf(v);
  } else {
    int t2 = t - 18432;
    int j = t2 & 7, lane = (t2 >> 3) & 63, f = t2 >> 9;
    int k = (f >> 1) * 32 + ((lane >> 4) * 8) + j;
    int n = (f & 1) * 16 + (lane & 15);
    w2f[t2] = f2bf(w2[k * 32 + n]);
  }
}

// ---------------------------------------------------------------------------
// MFMA decoder, CSR-ordered. Depth-2 gather pipeline (2 groups of row loads
// in flight per wave); dst rows nt-loaded (consumed once, CSR-hot) so L2
// capacity holds the randomly-reused src rows; sequential tmp output.
#define GPW 5
#define ZS 272
#define YS 72
#define NBLK 3125
#define BPX 391

__global__ __launch_bounds__(256, 4) void decoder_kernel(
    const ushort* __restrict__ hb,
    const int* __restrict__ srcp, const int* __restrict__ dstp,
    const ushort* __restrict__ eapb,
    const ushort* __restrict__ w1f, const ushort* __restrict__ w2f,
    const float* __restrict__ b1, const float* __restrict__ b2,
    const float* __restrict__ w3, const float* __restrict__ b3,
    float* __restrict__ tmp) {
  __shared__ ushort zbuf[4][16 * ZS];
  const int w = threadIdx.x >> 6, l = threadIdx.x & 63;
  const int sub = l & 15, quad = l >> 4;
  int bb = (blockIdx.x & 7) * BPX + (blockIdx.x >> 3);
  if (bb >= NBLK) return;
  ushort* Z = zbuf[w];
  ushort* Y = Z;

  float b1v[4];
#pragma unroll
  for (int t = 0; t < 4; t++) b1v[t] = b1[t * 16 + sub];
  float b2v0 = b2[sub], b2v1 = b2[16 + sub];
  float w3v0 = w3[sub], w3v1 = w3[16 + sub];
  float b3v = b3[0];

  const int gbase = (bb * 4 + w) * GPW;
  int sl[GPW], dl[GPW];
#pragma unroll
  for (int it = 0; it < GPW; it++) {
    int p = (gbase + it) * 16 + sub;
    sl[it] = __builtin_nontemporal_load(&srcp[p]);
    dl[it] = __builtin_nontemporal_load(&dstp[p]);
  }
  // depth-2 prefetch buffers
  uvec2 pa[2][4], pb[2][4];
  uint pe[2];
#pragma unroll
  for (int g = 0; g < 2; g++) {
#pragma unroll
    for (int i = 0; i < 4; i++) {
      int s = __shfl(sl[g], 4 * i + quad), d = __shfl(dl[g], 4 * i + quad);
      pa[g][i] = *(const uvec2*)&hb[(size_t)s * 64 + sub * 4];
      pb[g][i] = __builtin_nontemporal_load((const uvec2*)&hb[(size_t)d * 64 + sub * 4]);
    }
    pe[g] = __builtin_nontemporal_load((const uint*)eapb + (size_t)(gbase + g) * 64 + l);
  }

#pragma unroll
  for (int it = 0; it < GPW; it++) {
    const int buf = it & 1;
    // ---- stage Z from prefetched regs ----
#pragma unroll
    for (int i = 0; i < 4; i++) {
      int e = 4 * i + quad;
      uvec2 a = pa[buf][i], b = pb[buf][i];
      *(uvec2*)&Z[e * ZS + sub * 4] = a;
      *(uvec2*)&Z[e * ZS + 64 + sub * 4] = b;
      float a0 = bflo(a.x), a1 = bfhi(a.x), a2 = bflo(a.y), a3 = bfhi(a.y);
      float c0 = bflo(b.x), c1 = bfhi(b.x), c2 = bflo(b.y), c3 = bfhi(b.y);
      uvec2 u;
      u.x = pkbf(fabsf(a0 - c0), fabsf(a1 - c1));
      u.y = pkbf(fabsf(a2 - c2), fabsf(a3 - c3));
      *(uvec2*)&Z[e * ZS + 128 + sub * 4] = u;
      u.x = pkbf(a0 * c0, a1 * c1);
      u.y = pkbf(a2 * c2, a3 * c3);
      *(uvec2*)&Z[e * ZS + 192 + sub * 4] = u;
    }
    *(uint*)&Z[(l >> 2) * ZS + 256 + (l & 3) * 2] = pe[buf];

    // ---- refill the just-consumed buffer with group it+2 ----
    if (it + 2 < GPW) {
#pragma unroll
      for (int i = 0; i < 4; i++) {
        int s = __shfl(sl[it + 2], 4 * i + quad);
        int d = __shfl(dl[it + 2], 4 * i + quad);
        pa[buf][i] = *(const uvec2*)&hb[(size_t)s * 64 + sub * 4];
        pb[buf][i] = __builtin_nontemporal_load((const uvec2*)&hb[(size_t)d * 64 + sub * 4]);
      }
      pe[buf] = __builtin_nontemporal_load((const uint*)eapb +
                                           (size_t)(gbase + it + 2) * 64 + l);
    }

    // ---- GEMM1: Z(16x264) @ W1(264x64) ----
    f32x4 acc[4];
#pragma unroll
    for (int t = 0; t < 4; t++) acc[t] = (f32x4){0.f, 0.f, 0.f, 0.f};
#pragma unroll
    for (int s = 0; s < 8; s++) {
      bf16x8 af = *(const bf16x8*)&Z[sub * ZS + s * 32 + quad * 8];
#pragma unroll
      for (int t = 0; t < 4; t++)
        acc[t] = __builtin_amdgcn_mfma_f32_16x16x32_bf16(
            af, ((const bf16x8*)w1f)[(s * 4 + t) * 64 + l], acc[t], 0, 0, 0);
    }
    {
      bf16x8 af8 = (bf16x8){0, 0, 0, 0, 0, 0, 0, 0};
      if (quad == 0) af8 = *(const bf16x8*)&Z[sub * ZS + 256];
#pragma unroll
      for (int t = 0; t < 4; t++)
        acc[t] = __builtin_amdgcn_mfma_f32_16x16x32_bf16(
            af8, ((const bf16x8*)w1f)[(32 + t) * 64 + l], acc[t], 0, 0, 0);
    }
#pragma unroll
    for (int t = 0; t < 4; t++)
#pragma unroll
      for (int r = 0; r < 4; r++)
        Y[(quad * 4 + r) * YS + t * 16 + sub] = f2bf(fmaxf(acc[t][r] + b1v[t], 0.f));

    // ---- GEMM2: Y1(16x64) @ W2(64x32) ----
    f32x4 acc2[2];
    acc2[0] = (f32x4){0.f, 0.f, 0.f, 0.f};
    acc2[1] = (f32x4){0.f, 0.f, 0.f, 0.f};
#pragma unroll
    for (int ks = 0; ks < 2; ks++) {
      union { bf16x8 v; ushort4 u[2]; } ya;
      int o = sub * YS + ks * 32 + quad * 8;
      ya.u[0] = *(const ushort4*)&Y[o];
      ya.u[1] = *(const ushort4*)&Y[o + 4];
      acc2[0] = __builtin_amdgcn_mfma_f32_16x16x32_bf16(
          ya.v, ((const bf16x8*)w2f)[(ks * 2 + 0) * 64 + l], acc2[0], 0, 0, 0);
      acc2[1] = __builtin_amdgcn_mfma_f32_16x16x32_bf16(
          ya.v, ((const bf16x8*)w2f)[(ks * 2 + 1) * 64 + l], acc2[1], 0, 0, 0);
    }
    // ---- relu, W3 dot, reduce; sequential store to tmp ----
#pragma unroll
    for (int r = 0; r < 4; r++) {
      float o = fmaxf(acc2[0][r] + b2v0, 0.f) * w3v0 +
                fmaxf(acc2[1][r] + b2v1, 0.f) * w3v1;
      o += __shfl_xor(o, 1);
      o += __shfl_xor(o, 2);
      o += __shfl_xor(o, 4);
      o += __shfl_xor(o, 8);
      if (sub == 0) tmp[(gbase + it) * 16 + quad * 4 + r] = o + b3v;
    }
  }
}

// ---------------------------------------------------------------------------
extern "C" void kernel_launch(void* const* d_in, const int* in_sizes, int n_in,
                              void* d_out, int out_size, void* d_ws, size_t ws_size,
                              hipStream_t stream) {
  const float* x = (const float*)d_in[0];
  const int* ei = (const int*)d_in[1];
  const float* ea = (const float*)d_in[2];
  const float* l0_lin_w = (const float*)d_in[3];
  const float* l0_lin_b = (const float*)d_in[4];
  const float* l0_w1 = (const float*)d_in[5];
  const float* l0_b1 = (const float*)d_in[6];
  const float* l0_w2 = (const float*)d_in[7];
  const float* l0_b2 = (const float*)d_in[8];
  const float* l0_ln_g = (const float*)d_in[9];
  const float* l0_ln_b = (const float*)d_in[10];
  const float* l0_res_w = (const float*)d_in[11];
  const float* l0_res_b = (const float*)d_in[12];
  const float* dec_w1 = (const float*)d_in[29];
  const float* dec_b1 = (const float*)d_in[30];
  const float* dec_w2 = (const float*)d_in[31];
  const float* dec_b2 = (const float*)d_in[32];
  const float* dec_w3 = (const float*)d_in[33];
  const float* dec_b3 = (const float*)d_in[34];

  float* h_a = (float*)d_ws;                      // NN*64 f32
  float* h_b = h_a + (size_t)NN * 64;             // NN*64 f32
  ushort* hbA = (ushort*)(h_b + (size_t)NN * 64); // NN*64 bf16
  ushort* hbB = hbA + (size_t)NN * 64;            // NN*64 bf16
  int* ipos = (int*)(hbB + (size_t)NN * 64);      // NE
  int* srcp = ipos + NE;                          // NE
  int* dstp = srcp + NE;                          // NE
  float* tmp = (float*)(dstp + NE);               // NE f32 (sorted decoder out)
  int* off = (int*)(tmp + NE);                    // NN+1
  int* cnt = off + (NN + 1);                      // NN
  int* bsum = cnt + NN;                           // 256
  ushort* w1f = (ushort*)(bsum + 256);            // 18432 bf16
  ushort* w2f = w1f + 18432;                      // 2048 bf16
  ushort* eapb = w2f + 2048;                      // NE*8 bf16

  const int EB = (NE + 255) / 256;                // 3907
  const int SB = (NN + 256) / 256;                // 196

  // ---- CSR build ----
  hipMemsetAsync(cnt, 0, (size_t)NN * sizeof(int), stream);
  hist_kernel<<<EB, 256, 0, stream>>>(ei, cnt);
  scan1_kernel<<<SB, 256, 0, stream>>>(cnt, off, bsum);
  scan2_kernel<<<1, 256, 0, stream>>>(bsum, SB);
  scan3_kernel<<<SB, 256, 0, stream>>>(off, bsum, cnt);
  scatter_kernel<<<EB, 256, 0, stream>>>(ei, ea, off, cnt, ipos, srcp, dstp, eapb);

  // ---- fused GNN layers ----
  layer0_fused<<<NN / 4, 256, 0, stream>>>(x, h_a, hbA, eapb, srcp, off,
                                           l0_lin_w, l0_lin_b, l0_w1, l0_b1,
                                           l0_w2, l0_b2, l0_ln_g, l0_ln_b,
                                           l0_res_w, l0_res_b);
  layer_fused<<<NN / 4, 256, 0, stream>>>(hbA, h_a, h_b, hbB, eapb, srcp, off,
                                          (const float*)d_in[13], (const float*)d_in[14],
                                          (const float*)d_in[15], (const float*)d_in[16],
                                          (const float*)d_in[17], (const float*)d_in[18],
                                          (const float*)d_in[19], (const float*)d_in[20]);
  layer_fused<<<NN / 4, 256, 0, stream>>>(hbB, h_b, (float*)nullptr, hbA, eapb, srcp, off,
                                          (const float*)d_in[21], (const float*)d_in[22],
                                          (const float*)d_in[23], (const float*)d_in[24],
                                          (const float*)d_in[25], (const float*)d_in[26],
                                          (const float*)d_in[27], (const float*)d_in[28]);

  // ---- decoder ----
  prep_kernel<<<80, 256, 0, stream>>>(dec_w1, dec_w2, w1f, w2f);
  decoder_kernel<<<8 * BPX, 256, 0, stream>>>(hbA, srcp, dstp, eapb,
                                              w1f, w2f, dec_b1, dec_b2,
                                              dec_w3, dec_b3, tmp);
  unperm_kernel<<<EB, 256, 0, stream>>>(tmp, ipos, (float*)d_out);
}

// Round 11
// 817.696 us; speedup vs baseline: 1.0061x; 1.0061x over previous
//
#include <hip/hip_runtime.h>

#define NN 50000
#define NE 1000000

constexpr float LN_EPS = 1e-5f;

typedef short bf16x8 __attribute__((ext_vector_type(8)));
typedef float f32x4 __attribute__((ext_vector_type(4)));
typedef uint uvec4 __attribute__((ext_vector_type(4)));
typedef uint uvec2 __attribute__((ext_vector_type(2)));

// round-to-nearest-even float -> bf16
__device__ inline ushort f2bf(float x) {
  union { float f; uint u; } v; v.f = x;
  uint r = v.u + 0x7fffu + ((v.u >> 16) & 1u);
  return (ushort)(r >> 16);
}
__device__ inline uint pkbf(float a, float b) {
  union { float f; uint u; } x, y; x.f = a; y.f = b;
  uint ra = (x.u + 0x7fffu + ((x.u >> 16) & 1u)) >> 16;
  uint rb = (y.u + 0x7fffu + ((y.u >> 16) & 1u)) & 0xffff0000u;
  return ra | rb;
}
__device__ inline float bflo(uint u) { union { uint x; float f; } v; v.x = u << 16; return v.f; }
__device__ inline float bfhi(uint u) { union { uint x; float f; } v; v.x = u & 0xffff0000u; return v.f; }
__device__ inline void ea8(uvec4 E, float* o) {
  o[0] = bflo(E.x); o[1] = bfhi(E.x); o[2] = bflo(E.y); o[3] = bfhi(E.y);
  o[4] = bflo(E.z); o[5] = bfhi(E.z); o[6] = bflo(E.w); o[7] = bfhi(E.w);
}

// ---------------------------------------------------------------------------
// CSR build: histogram -> exclusive scan -> scatter.
__global__ __launch_bounds__(256) void hist_kernel(const int* __restrict__ ei,
                                                   int* __restrict__ cnt) {
  int e = blockIdx.x * 256 + threadIdx.x;
  if (e < NE) atomicAdd(&cnt[ei[NE + e]], 1);
}

__global__ __launch_bounds__(256) void scan1_kernel(const int* __restrict__ cnt,
                                                    int* __restrict__ off,
                                                    int* __restrict__ bsum) {
  __shared__ int sh[256];
  int t = threadIdx.x;
  int idx = blockIdx.x * 256 + t;
  int v = (idx < NN) ? cnt[idx] : 0;
  sh[t] = v;
  __syncthreads();
  for (int o = 1; o < 256; o <<= 1) {
    int xv = (t >= o) ? sh[t - o] : 0;
    __syncthreads();
    sh[t] += xv;
    __syncthreads();
  }
  if (idx <= NN) off[idx] = sh[t] - v;
  if (t == 255) bsum[blockIdx.x] = sh[255];
}

__global__ __launch_bounds__(256) void scan2_kernel(int* __restrict__ bsum, int nb) {
  __shared__ int sh[256];
  int t = threadIdx.x;
  int v = (t < nb) ? bsum[t] : 0;
  sh[t] = v;
  __syncthreads();
  for (int o = 1; o < 256; o <<= 1) {
    int xv = (t >= o) ? sh[t - o] : 0;
    __syncthreads();
    sh[t] += xv;
    __syncthreads();
  }
  if (t < nb) bsum[t] = sh[t] - v;
}

__global__ __launch_bounds__(256) void scan3_kernel(int* __restrict__ off,
                                                    const int* __restrict__ bsum,
                                                    int* __restrict__ cnt) {
  int idx = blockIdx.x * 256 + threadIdx.x;
  if (idx <= NN) off[idx] += bsum[blockIdx.x];
  if (idx < NN) cnt[idx] = 0;
}

// scatter emits: srcp/dstp (sorted endpoint ids), eapb (dst-sorted bf16 edge
// attrs), ipos (edge -> sorted position inverse map, coalesced by e).
__global__ __launch_bounds__(256) void scatter_kernel(
    const int* __restrict__ ei, const float* __restrict__ ea,
    const int* __restrict__ off, int* __restrict__ cur,
    int* __restrict__ ipos, int* __restrict__ srcp, int* __restrict__ dstp,
    ushort* __restrict__ eapb) {
  int e = blockIdx.x * 256 + threadIdx.x;
  if (e < NE) {
    int d = ei[NE + e];
    int s = ei[e];
    int p = off[d] + atomicAdd(&cur[d], 1);
    ipos[e] = p;
    srcp[p] = s;
    dstp[p] = d;
    const float* eaf = ea + (size_t)e * 8;
    uvec4 u;
    u.x = pkbf(eaf[0], eaf[1]);
    u.y = pkbf(eaf[2], eaf[3]);
    u.z = pkbf(eaf[4], eaf[5]);
    u.w = pkbf(eaf[6], eaf[7]);
    __builtin_nontemporal_store(u, (uvec4*)(eapb + (size_t)p * 8));
  }
}

// unpermute: coalesced write of out, random 4B read of the 4MB tmp table.
__global__ __launch_bounds__(256) void unperm_kernel(const float* __restrict__ tmp,
                                                     const int* __restrict__ ipos,
                                                     float* __restrict__ out) {
  int e = blockIdx.x * 256 + threadIdx.x;
  if (e < NE) out[e] = tmp[ipos[e]];
}

// ---------------------------------------------------------------------------
__device__ inline float lane_layernorm(float r, float g, float b) {
  float s = r;
#pragma unroll
  for (int m = 32; m >= 1; m >>= 1) s += __shfl_xor(s, m);
  float mu = s * (1.f / 64.f);
  float dv = r - mu;
  float v = dv * dv;
#pragma unroll
  for (int m = 32; m >= 1; m >>= 1) v += __shfl_xor(v, m);
  float var = v * (1.f / 64.f);
  return dv * rsqrtf(var + LN_EPS) * g + b;
}

// ---------------------------------------------------------------------------
// Fused layer 0 (D=16): aggregation + MLP + residual Linear + LN.
__global__ __launch_bounds__(256) void layer0_fused(
    const float* __restrict__ x, float* __restrict__ hout,
    ushort* __restrict__ houtbf,
    const ushort* __restrict__ eapb, const int* __restrict__ srcp,
    const int* __restrict__ off,
    const float* __restrict__ lw, const float* __restrict__ lb,
    const float* __restrict__ w1, const float* __restrict__ b1,
    const float* __restrict__ w2, const float* __restrict__ b2,
    const float* __restrict__ lng, const float* __restrict__ lnb,
    const float* __restrict__ rw, const float* __restrict__ rb) {
  int n = blockIdx.x * 4 + (threadIdx.x >> 6);
  int j = threadIdx.x & 63;
  int d = j & 15, slot = j >> 4;
  int start = off[n], end = off[n + 1];
  float lwv[8];
#pragma unroll
  for (int i = 0; i < 8; i++) lwv[i] = lw[i * 16 + d];
  float lbv = lb[d];
  float acc = 0.f;
  for (int base = start; base < end; base += 64) {
    int idx = base + j;
    int sl = (idx < end) ? srcp[idx] : 0;
    int c = min(end - base, 64);
    for (int i0 = 0; i0 < c; i0 += 4) {
      int i = i0 + slot;
      bool valid = i < c;
      int ii = i & 63;
      int s = __shfl(sl, ii);
      int pp = min(base + i0 + slot, NE - 1);
      float ev = bflo((uint)eapb[(size_t)pp * 8 + (d & 7)]);
      float xs = x[(size_t)s * 16 + d];
      float m = lbv + xs;
#pragma unroll
      for (int q = 0; q < 8; q++) m = fmaf(__shfl(ev, slot * 16 + q), lwv[q], m);
      m = fmaxf(m, 0.f);
      acc += valid ? m : 0.f;
    }
  }
  acc += __shfl_xor(acc, 16);
  acc += __shfl_xor(acc, 32);
  float xr = x[(size_t)n * 16 + d];
  float t = xr + acc;
  float q1 = b1[j];
#pragma unroll 4
  for (int k = 0; k < 16; k++) q1 = fmaf(__shfl(t, k), w1[k * 64 + j], q1);
  q1 = fmaxf(q1, 0.f);
  float h2 = b2[j];
  for (int k = 0; k < 64; k++) h2 = fmaf(__shfl(q1, k), w2[k * 64 + j], h2);
  h2 = fmaxf(h2, 0.f);
  float res = rb[j];
#pragma unroll 4
  for (int k = 0; k < 16; k++) res = fmaf(__shfl(xr, k), rw[k * 64 + j], res);
  float v = lane_layernorm(h2 + res, lng[j], lnb[j]);
  hout[(size_t)n * 64 + j] = v;
  houtbf[(size_t)n * 64 + j] = f2bf(v);
}

// ---------------------------------------------------------------------------
// Fused layers 1/2 (D=64): bf16 h gathers; eapb/srcp/hinf consumed once ->
// nt loads so the hinb gather table stays L2-resident.
__global__ __launch_bounds__(256) void layer_fused(
    const ushort* __restrict__ hinb, const float* __restrict__ hinf,
    float* __restrict__ houtf, ushort* __restrict__ houtbf,
    const ushort* __restrict__ eapb, const int* __restrict__ srcp,
    const int* __restrict__ off,
    const float* __restrict__ lw, const float* __restrict__ lb,
    const float* __restrict__ w1, const float* __restrict__ b1,
    const float* __restrict__ w2, const float* __restrict__ b2,
    const float* __restrict__ lng, const float* __restrict__ lnb) {
  int n = blockIdx.x * 4 + (threadIdx.x >> 6);
  int j = threadIdx.x & 63;
  int start = off[n], end = off[n + 1];
  float lwv[8];
#pragma unroll
  for (int i = 0; i < 8; i++) lwv[i] = lw[i * 64 + j];
  float lbv = lb[j];
  float acc = 0.f;
  for (int base = start; base < end; base += 64) {
    int idx = base + j;
    int sl = (idx < end) ? __builtin_nontemporal_load(&srcp[idx]) : 0;
    int c = min(end - base, 64);
    int i = 0;
    for (; i + 4 <= c; i += 4) {
      int s0 = __builtin_amdgcn_readfirstlane(__shfl(sl, i));
      int s1 = __builtin_amdgcn_readfirstlane(__shfl(sl, i + 1));
      int s2 = __builtin_amdgcn_readfirstlane(__shfl(sl, i + 2));
      int s3 = __builtin_amdgcn_readfirstlane(__shfl(sl, i + 3));
      float h0 = bflo((uint)hinb[(size_t)s0 * 64 + j]);
      float h1 = bflo((uint)hinb[(size_t)s1 * 64 + j]);
      float h2v = bflo((uint)hinb[(size_t)s2 * 64 + j]);
      float h3 = bflo((uint)hinb[(size_t)s3 * 64 + j]);
      const uvec4* ep = (const uvec4*)(eapb + (size_t)(base + i) * 8);
      uvec4 E0 = __builtin_nontemporal_load(ep + 0);
      uvec4 E1 = __builtin_nontemporal_load(ep + 1);
      uvec4 E2 = __builtin_nontemporal_load(ep + 2);
      uvec4 E3 = __builtin_nontemporal_load(ep + 3);
      float a0[8], a1[8], a2[8], a3[8];
      ea8(E0, a0); ea8(E1, a1); ea8(E2, a2); ea8(E3, a3);
      float m0 = lbv + h0, m1 = lbv + h1, m2 = lbv + h2v, m3 = lbv + h3;
#pragma unroll
      for (int q = 0; q < 8; q++) {
        m0 = fmaf(a0[q], lwv[q], m0);
        m1 = fmaf(a1[q], lwv[q], m1);
        m2 = fmaf(a2[q], lwv[q], m2);
        m3 = fmaf(a3[q], lwv[q], m3);
      }
      acc += fmaxf(m0, 0.f) + fmaxf(m1, 0.f) + fmaxf(m2, 0.f) + fmaxf(m3, 0.f);
    }
    for (; i < c; i++) {
      int s = __builtin_amdgcn_readfirstlane(__shfl(sl, i));
      float hc = bflo((uint)hinb[(size_t)s * 64 + j]);
      uvec4 E = __builtin_nontemporal_load((const uvec4*)(eapb + (size_t)(base + i) * 8));
      float a[8];
      ea8(E, a);
      float m = lbv + hc;
#pragma unroll
      for (int q = 0; q < 8; q++) m = fmaf(a[q], lwv[q], m);
      acc += fmaxf(m, 0.f);
    }
  }
  float hv = __builtin_nontemporal_load(&hinf[(size_t)n * 64 + j]);
  float t = hv + acc;
  float q1 = b1[j];
  for (int k = 0; k < 64; k++) q1 = fmaf(__shfl(t, k), w1[k * 64 + j], q1);
  q1 = fmaxf(q1, 0.f);
  float h2 = b2[j];
  for (int k = 0; k < 64; k++) h2 = fmaf(__shfl(q1, k), w2[k * 64 + j], h2);
  h2 = fmaxf(h2, 0.f);
  float v = lane_layernorm(h2 + hv, lng[j], lnb[j]);
  if (houtf) houtf[(size_t)n * 64 + j] = v;
  houtbf[(size_t)n * 64 + j] = f2bf(v);
}

// ---------------------------------------------------------------------------
// Prep: dec_w1 (264x64, K zero-padded to 288) and dec_w2 (64x32) into per-lane
// bf16 B-fragments for mfma_f32_16x16x32_bf16.
__global__ __launch_bounds__(256) void prep_kernel(
    const float* __restrict__ w1, const float* __restrict__ w2,
    ushort* __restrict__ w1f, ushort* __restrict__ w2f) {
  int t = blockIdx.x * 256 + threadIdx.x;
  if (t < 18432) {
    int j = t & 7, lane = (t >> 3) & 63, f = t >> 9;
    int k = (f >> 2) * 32 + ((lane >> 4) * 8) + j;
    int n = (f & 3) * 16 + (lane & 15);
    float v = (k < 264) ? w1[k * 64 + n] : 0.f;
    w1f[t] = f2bf(v);
  } else {
    int t2 = t - 18432;
    int j = t2 & 7, lane = (t2 >> 3) & 63, f = t2 >> 9;
    int k = (f >> 1) * 32 + ((lane >> 4) * 8) + j;
    int n = (f & 1) * 16 + (lane & 15);
    w2f[t2] = f2bf(w2[k * 32 + n]);
  }
}

// ---------------------------------------------------------------------------
// MFMA decoder, CSR-ordered. Depth-2 gather pipeline with REGULAR (cached)
// hb loads — dst rows are reused across consecutive groups (R10 lesson: nt
// on them re-fetches from HBM). nt only on stream-once srcp/dstp/eapb.
#define GPW 5
#define ZS 272
#define YS 72
#define NBLK 3125
#define BPX 391

__global__ __launch_bounds__(256, 4) void decoder_kernel(
    const ushort* __restrict__ hb,
    const int* __restrict__ srcp, const int* __restrict__ dstp,
    const ushort* __restrict__ eapb,
    const ushort* __restrict__ w1f, const ushort* __restrict__ w2f,
    const float* __restrict__ b1, const float* __restrict__ b2,
    const float* __restrict__ w3, const float* __restrict__ b3,
    float* __restrict__ tmp) {
  __shared__ ushort zbuf[4][16 * ZS];
  const int w = threadIdx.x >> 6, l = threadIdx.x & 63;
  const int sub = l & 15, quad = l >> 4;
  int bb = (blockIdx.x & 7) * BPX + (blockIdx.x >> 3);
  if (bb >= NBLK) return;
  ushort* Z = zbuf[w];
  ushort* Y = Z;

  float b1v[4];
#pragma unroll
  for (int t = 0; t < 4; t++) b1v[t] = b1[t * 16 + sub];
  float b2v0 = b2[sub], b2v1 = b2[16 + sub];
  float w3v0 = w3[sub], w3v1 = w3[16 + sub];
  float b3v = b3[0];

  const int gbase = (bb * 4 + w) * GPW;
  int sl[GPW], dl[GPW];
#pragma unroll
  for (int it = 0; it < GPW; it++) {
    int p = (gbase + it) * 16 + sub;
    sl[it] = __builtin_nontemporal_load(&srcp[p]);
    dl[it] = __builtin_nontemporal_load(&dstp[p]);
  }
  // depth-2 prefetch buffers (regular cached loads for hb rows)
  uvec2 pa[2][4], pb[2][4];
  uint pe[2];
#pragma unroll
  for (int g = 0; g < 2; g++) {
#pragma unroll
    for (int i = 0; i < 4; i++) {
      int s = __shfl(sl[g], 4 * i + quad), d = __shfl(dl[g], 4 * i + quad);
      pa[g][i] = *(const uvec2*)&hb[(size_t)s * 64 + sub * 4];
      pb[g][i] = *(const uvec2*)&hb[(size_t)d * 64 + sub * 4];
    }
    pe[g] = __builtin_nontemporal_load((const uint*)eapb + (size_t)(gbase + g) * 64 + l);
  }

#pragma unroll
  for (int it = 0; it < GPW; it++) {
    const int buf = it & 1;
    // ---- stage Z from prefetched regs ----
#pragma unroll
    for (int i = 0; i < 4; i++) {
      int e = 4 * i + quad;
      uvec2 a = pa[buf][i], b = pb[buf][i];
      *(uvec2*)&Z[e * ZS + sub * 4] = a;
      *(uvec2*)&Z[e * ZS + 64 + sub * 4] = b;
      float a0 = bflo(a.x), a1 = bfhi(a.x), a2 = bflo(a.y), a3 = bfhi(a.y);
      float c0 = bflo(b.x), c1 = bfhi(b.x), c2 = bflo(b.y), c3 = bfhi(b.y);
      uvec2 u;
      u.x = pkbf(fabsf(a0 - c0), fabsf(a1 - c1));
      u.y = pkbf(fabsf(a2 - c2), fabsf(a3 - c3));
      *(uvec2*)&Z[e * ZS + 128 + sub * 4] = u;
      u.x = pkbf(a0 * c0, a1 * c1);
      u.y = pkbf(a2 * c2, a3 * c3);
      *(uvec2*)&Z[e * ZS + 192 + sub * 4] = u;
    }
    *(uint*)&Z[(l >> 2) * ZS + 256 + (l & 3) * 2] = pe[buf];

    // ---- refill the just-consumed buffer with group it+2 ----
    if (it + 2 < GPW) {
#pragma unroll
      for (int i = 0; i < 4; i++) {
        int s = __shfl(sl[it + 2], 4 * i + quad);
        int d = __shfl(dl[it + 2], 4 * i + quad);
        pa[buf][i] = *(const uvec2*)&hb[(size_t)s * 64 + sub * 4];
        pb[buf][i] = *(const uvec2*)&hb[(size_t)d * 64 + sub * 4];
      }
      pe[buf] = __builtin_nontemporal_load((const uint*)eapb +
                                           (size_t)(gbase + it + 2) * 64 + l);
    }

    // ---- GEMM1: Z(16x264) @ W1(264x64) ----
    f32x4 acc[4];
#pragma unroll
    for (int t = 0; t < 4; t++) acc[t] = (f32x4){0.f, 0.f, 0.f, 0.f};
#pragma unroll
    for (int s = 0; s < 8; s++) {
      bf16x8 af = *(const bf16x8*)&Z[sub * ZS + s * 32 + quad * 8];
#pragma unroll
      for (int t = 0; t < 4; t++)
        acc[t] = __builtin_amdgcn_mfma_f32_16x16x32_bf16(
            af, ((const bf16x8*)w1f)[(s * 4 + t) * 64 + l], acc[t], 0, 0, 0);
    }
    {
      bf16x8 af8 = (bf16x8){0, 0, 0, 0, 0, 0, 0, 0};
      if (quad == 0) af8 = *(const bf16x8*)&Z[sub * ZS + 256];
#pragma unroll
      for (int t = 0; t < 4; t++)
        acc[t] = __builtin_amdgcn_mfma_f32_16x16x32_bf16(
            af8, ((const bf16x8*)w1f)[(32 + t) * 64 + l], acc[t], 0, 0, 0);
    }
#pragma unroll
    for (int t = 0; t < 4; t++)
#pragma unroll
      for (int r = 0; r < 4; r++)
        Y[(quad * 4 + r) * YS + t * 16 + sub] = f2bf(fmaxf(acc[t][r] + b1v[t], 0.f));

    // ---- GEMM2: Y1(16x64) @ W2(64x32) ----
    f32x4 acc2[2];
    acc2[0] = (f32x4){0.f, 0.f, 0.f, 0.f};
    acc2[1] = (f32x4){0.f, 0.f, 0.f, 0.f};
#pragma unroll
    for (int ks = 0; ks < 2; ks++) {
      union { bf16x8 v; ushort4 u[2]; } ya;
      int o = sub * YS + ks * 32 + quad * 8;
      ya.u[0] = *(const ushort4*)&Y[o];
      ya.u[1] = *(const ushort4*)&Y[o + 4];
      acc2[0] = __builtin_amdgcn_mfma_f32_16x16x32_bf16(
          ya.v, ((const bf16x8*)w2f)[(ks * 2 + 0) * 64 + l], acc2[0], 0, 0, 0);
      acc2[1] = __builtin_amdgcn_mfma_f32_16x16x32_bf16(
          ya.v, ((const bf16x8*)w2f)[(ks * 2 + 1) * 64 + l], acc2[1], 0, 0, 0);
    }
    // ---- relu, W3 dot, reduce; sequential store to tmp ----
#pragma unroll
    for (int r = 0; r < 4; r++) {
      float o = fmaxf(acc2[0][r] + b2v0, 0.f) * w3v0 +
                fmaxf(acc2[1][r] + b2v1, 0.f) * w3v1;
      o += __shfl_xor(o, 1);
      o += __shfl_xor(o, 2);
      o += __shfl_xor(o, 4);
      o += __shfl_xor(o, 8);
      if (sub == 0) tmp[(gbase + it) * 16 + quad * 4 + r] = o + b3v;
    }
  }
}

// ---------------------------------------------------------------------------
extern "C" void kernel_launch(void* const* d_in, const int* in_sizes, int n_in,
                              void* d_out, int out_size, void* d_ws, size_t ws_size,
                              hipStream_t stream) {
  const float* x = (const float*)d_in[0];
  const int* ei = (const int*)d_in[1];
  const float* ea = (const float*)d_in[2];
  const float* l0_lin_w = (const float*)d_in[3];
  const float* l0_lin_b = (const float*)d_in[4];
  const float* l0_w1 = (const float*)d_in[5];
  const float* l0_b1 = (const float*)d_in[6];
  const float* l0_w2 = (const float*)d_in[7];
  const float* l0_b2 = (const float*)d_in[8];
  const float* l0_ln_g = (const float*)d_in[9];
  const float* l0_ln_b = (const float*)d_in[10];
  const float* l0_res_w = (const float*)d_in[11];
  const float* l0_res_b = (const float*)d_in[12];
  const float* dec_w1 = (const float*)d_in[29];
  const float* dec_b1 = (const float*)d_in[30];
  const float* dec_w2 = (const float*)d_in[31];
  const float* dec_b2 = (const float*)d_in[32];
  const float* dec_w3 = (const float*)d_in[33];
  const float* dec_b3 = (const float*)d_in[34];

  float* h_a = (float*)d_ws;                      // NN*64 f32
  float* h_b = h_a + (size_t)NN * 64;             // NN*64 f32
  ushort* hbA = (ushort*)(h_b + (size_t)NN * 64); // NN*64 bf16
  ushort* hbB = hbA + (size_t)NN * 64;            // NN*64 bf16
  int* ipos = (int*)(hbB + (size_t)NN * 64);      // NE
  int* srcp = ipos + NE;                          // NE
  int* dstp = srcp + NE;                          // NE
  float* tmp = (float*)(dstp + NE);               // NE f32 (sorted decoder out)
  int* off = (int*)(tmp + NE);                    // NN+1
  int* cnt = off + (NN + 1);                      // NN
  int* bsum = cnt + NN;                           // 256
  ushort* w1f = (ushort*)(bsum + 256);            // 18432 bf16
  ushort* w2f = w1f + 18432;                      // 2048 bf16
  ushort* eapb = w2f + 2048;                      // NE*8 bf16

  const int EB = (NE + 255) / 256;                // 3907
  const int SB = (NN + 256) / 256;                // 196

  // ---- CSR build ----
  hipMemsetAsync(cnt, 0, (size_t)NN * sizeof(int), stream);
  hist_kernel<<<EB, 256, 0, stream>>>(ei, cnt);
  scan1_kernel<<<SB, 256, 0, stream>>>(cnt, off, bsum);
  scan2_kernel<<<1, 256, 0, stream>>>(bsum, SB);
  scan3_kernel<<<SB, 256, 0, stream>>>(off, bsum, cnt);
  scatter_kernel<<<EB, 256, 0, stream>>>(ei, ea, off, cnt, ipos, srcp, dstp, eapb);

  // ---- fused GNN layers ----
  layer0_fused<<<NN / 4, 256, 0, stream>>>(x, h_a, hbA, eapb, srcp, off,
                                           l0_lin_w, l0_lin_b, l0_w1, l0_b1,
                                           l0_w2, l0_b2, l0_ln_g, l0_ln_b,
                                           l0_res_w, l0_res_b);
  layer_fused<<<NN / 4, 256, 0, stream>>>(hbA, h_a, h_b, hbB, eapb, srcp, off,
                                          (const float*)d_in[13], (const float*)d_in[14],
                                          (const float*)d_in[15], (const float*)d_in[16],
                                          (const float*)d_in[17], (const float*)d_in[18],
                                          (const float*)d_in[19], (const float*)d_in[20]);
  layer_fused<<<NN / 4, 256, 0, stream>>>(hbB, h_b, (float*)nullptr, hbA, eapb, srcp, off,
                                          (const float*)d_in[21], (const float*)d_in[22],
                                          (const float*)d_in[23], (const float*)d_in[24],
                                          (const float*)d_in[25], (const float*)d_in[26],
                                          (const float*)d_in[27], (const float*)d_in[28]);

  // ---- decoder ----
  prep_kernel<<<80, 256, 0, stream>>>(dec_w1, dec_w2, w1f, w2f);
  decoder_kernel<<<8 * BPX, 256, 0, stream>>>(hbA, srcp, dstp, eapb,
                                              w1f, w2f, dec_b1, dec_b2,
                                              dec_w3, dec_b3, tmp);
  unperm_kernel<<<EB, 256, 0, stream>>>(tmp, ipos, (float*)d_out);
}

// Round 12
// 701.094 us; speedup vs baseline: 1.1734x; 1.1663x over previous
//
#include <hip/hip_runtime.h>

#define NN 50000
#define NE 1000000

constexpr float LN_EPS = 1e-5f;

typedef short bf16x8 __attribute__((ext_vector_type(8)));
typedef float f32x4 __attribute__((ext_vector_type(4)));
typedef uint uvec4 __attribute__((ext_vector_type(4)));
typedef uint uvec2 __attribute__((ext_vector_type(2)));

// round-to-nearest-even float -> bf16
__device__ inline ushort f2bf(float x) {
  union { float f; uint u; } v; v.f = x;
  uint r = v.u + 0x7fffu + ((v.u >> 16) & 1u);
  return (ushort)(r >> 16);
}
__device__ inline uint pkbf(float a, float b) {
  union { float f; uint u; } x, y; x.f = a; y.f = b;
  uint ra = (x.u + 0x7fffu + ((x.u >> 16) & 1u)) >> 16;
  uint rb = (y.u + 0x7fffu + ((y.u >> 16) & 1u)) & 0xffff0000u;
  return ra | rb;
}
__device__ inline float bflo(uint u) { union { uint x; float f; } v; v.x = u << 16; return v.f; }
__device__ inline float bfhi(uint u) { union { uint x; float f; } v; v.x = u & 0xffff0000u; return v.f; }
__device__ inline void ea8(uvec4 E, float* o) {
  o[0] = bflo(E.x); o[1] = bfhi(E.x); o[2] = bflo(E.y); o[3] = bfhi(E.y);
  o[4] = bflo(E.z); o[5] = bfhi(E.z); o[6] = bflo(E.w); o[7] = bfhi(E.w);
}

// ---------------------------------------------------------------------------
// CSR build: histogram -> exclusive scan -> scatter.
__global__ __launch_bounds__(256) void hist_kernel(const int* __restrict__ ei,
                                                   int* __restrict__ cnt) {
  int e = blockIdx.x * 256 + threadIdx.x;
  if (e < NE) atomicAdd(&cnt[ei[NE + e]], 1);
}

__global__ __launch_bounds__(256) void scan1_kernel(const int* __restrict__ cnt,
                                                    int* __restrict__ off,
                                                    int* __restrict__ bsum) {
  __shared__ int sh[256];
  int t = threadIdx.x;
  int idx = blockIdx.x * 256 + t;
  int v = (idx < NN) ? cnt[idx] : 0;
  sh[t] = v;
  __syncthreads();
  for (int o = 1; o < 256; o <<= 1) {
    int xv = (t >= o) ? sh[t - o] : 0;
    __syncthreads();
    sh[t] += xv;
    __syncthreads();
  }
  if (idx <= NN) off[idx] = sh[t] - v;
  if (t == 255) bsum[blockIdx.x] = sh[255];
}

__global__ __launch_bounds__(256) void scan2_kernel(int* __restrict__ bsum, int nb) {
  __shared__ int sh[256];
  int t = threadIdx.x;
  int v = (t < nb) ? bsum[t] : 0;
  sh[t] = v;
  __syncthreads();
  for (int o = 1; o < 256; o <<= 1) {
    int xv = (t >= o) ? sh[t - o] : 0;
    __syncthreads();
    sh[t] += xv;
    __syncthreads();
  }
  if (t < nb) bsum[t] = sh[t] - v;
}

__global__ __launch_bounds__(256) void scan3_kernel(int* __restrict__ off,
                                                    const int* __restrict__ bsum,
                                                    int* __restrict__ cnt) {
  int idx = blockIdx.x * 256 + threadIdx.x;
  if (idx <= NN) off[idx] += bsum[blockIdx.x];
  if (idx < NN) cnt[idx] = 0;
}

// scatter emits: srcp/dstp (sorted endpoint ids), eapb (dst-sorted bf16 edge
// attrs), ipos (edge -> sorted position inverse map, coalesced by e).
__global__ __launch_bounds__(256) void scatter_kernel(
    const int* __restrict__ ei, const float* __restrict__ ea,
    const int* __restrict__ off, int* __restrict__ cur,
    int* __restrict__ ipos, int* __restrict__ srcp, int* __restrict__ dstp,
    ushort* __restrict__ eapb) {
  int e = blockIdx.x * 256 + threadIdx.x;
  if (e < NE) {
    int d = ei[NE + e];
    int s = ei[e];
    int p = off[d] + atomicAdd(&cur[d], 1);
    ipos[e] = p;
    srcp[p] = s;
    dstp[p] = d;
    const float* eaf = ea + (size_t)e * 8;
    uvec4 u;
    u.x = pkbf(eaf[0], eaf[1]);
    u.y = pkbf(eaf[2], eaf[3]);
    u.z = pkbf(eaf[4], eaf[5]);
    u.w = pkbf(eaf[6], eaf[7]);
    __builtin_nontemporal_store(u, (uvec4*)(eapb + (size_t)p * 8));
  }
}

// unpermute: coalesced write of out, random 4B read of the 4MB tmp table.
__global__ __launch_bounds__(256) void unperm_kernel(const float* __restrict__ tmp,
                                                     const int* __restrict__ ipos,
                                                     float* __restrict__ out) {
  int e = blockIdx.x * 256 + threadIdx.x;
  if (e < NE) out[e] = tmp[ipos[e]];
}

// ---------------------------------------------------------------------------
__device__ inline float lane_layernorm(float r, float g, float b) {
  float s = r;
#pragma unroll
  for (int m = 32; m >= 1; m >>= 1) s += __shfl_xor(s, m);
  float mu = s * (1.f / 64.f);
  float dv = r - mu;
  float v = dv * dv;
#pragma unroll
  for (int m = 32; m >= 1; m >>= 1) v += __shfl_xor(v, m);
  float var = v * (1.f / 64.f);
  return dv * rsqrtf(var + LN_EPS) * g + b;
}

// ---------------------------------------------------------------------------
// Fused layer 0 (D=16): aggregation + MLP + residual Linear + LN.
__global__ __launch_bounds__(256) void layer0_fused(
    const float* __restrict__ x, float* __restrict__ hout,
    ushort* __restrict__ houtbf,
    const ushort* __restrict__ eapb, const int* __restrict__ srcp,
    const int* __restrict__ off,
    const float* __restrict__ lw, const float* __restrict__ lb,
    const float* __restrict__ w1, const float* __restrict__ b1,
    const float* __restrict__ w2, const float* __restrict__ b2,
    const float* __restrict__ lng, const float* __restrict__ lnb,
    const float* __restrict__ rw, const float* __restrict__ rb) {
  int n = blockIdx.x * 4 + (threadIdx.x >> 6);
  int j = threadIdx.x & 63;
  int d = j & 15, slot = j >> 4;
  int start = off[n], end = off[n + 1];
  float lwv[8];
#pragma unroll
  for (int i = 0; i < 8; i++) lwv[i] = lw[i * 16 + d];
  float lbv = lb[d];
  float acc = 0.f;
  for (int base = start; base < end; base += 64) {
    int idx = base + j;
    int sl = (idx < end) ? srcp[idx] : 0;
    int c = min(end - base, 64);
    for (int i0 = 0; i0 < c; i0 += 4) {
      int i = i0 + slot;
      bool valid = i < c;
      int ii = i & 63;
      int s = __shfl(sl, ii);
      int pp = min(base + i0 + slot, NE - 1);
      float ev = bflo((uint)eapb[(size_t)pp * 8 + (d & 7)]);
      float xs = x[(size_t)s * 16 + d];
      float m = lbv + xs;
#pragma unroll
      for (int q = 0; q < 8; q++) m = fmaf(__shfl(ev, slot * 16 + q), lwv[q], m);
      m = fmaxf(m, 0.f);
      acc += valid ? m : 0.f;
    }
  }
  acc += __shfl_xor(acc, 16);
  acc += __shfl_xor(acc, 32);
  float xr = x[(size_t)n * 16 + d];
  float t = xr + acc;
  float q1 = b1[j];
#pragma unroll 4
  for (int k = 0; k < 16; k++) q1 = fmaf(__shfl(t, k), w1[k * 64 + j], q1);
  q1 = fmaxf(q1, 0.f);
  float h2 = b2[j];
  for (int k = 0; k < 64; k++) h2 = fmaf(__shfl(q1, k), w2[k * 64 + j], h2);
  h2 = fmaxf(h2, 0.f);
  float res = rb[j];
#pragma unroll 4
  for (int k = 0; k < 16; k++) res = fmaf(__shfl(xr, k), rw[k * 64 + j], res);
  float v = lane_layernorm(h2 + res, lng[j], lnb[j]);
  hout[(size_t)n * 64 + j] = v;
  houtbf[(size_t)n * 64 + j] = f2bf(v);
}

// ---------------------------------------------------------------------------
// Fused layers 1/2 (D=64): bf16 h gathers; eapb/srcp/hinf consumed once ->
// nt loads so the hinb gather table stays L2-resident.
__global__ __launch_bounds__(256) void layer_fused(
    const ushort* __restrict__ hinb, const float* __restrict__ hinf,
    float* __restrict__ houtf, ushort* __restrict__ houtbf,
    const ushort* __restrict__ eapb, const int* __restrict__ srcp,
    const int* __restrict__ off,
    const float* __restrict__ lw, const float* __restrict__ lb,
    const float* __restrict__ w1, const float* __restrict__ b1,
    const float* __restrict__ w2, const float* __restrict__ b2,
    const float* __restrict__ lng, const float* __restrict__ lnb) {
  int n = blockIdx.x * 4 + (threadIdx.x >> 6);
  int j = threadIdx.x & 63;
  int start = off[n], end = off[n + 1];
  float lwv[8];
#pragma unroll
  for (int i = 0; i < 8; i++) lwv[i] = lw[i * 64 + j];
  float lbv = lb[j];
  float acc = 0.f;
  for (int base = start; base < end; base += 64) {
    int idx = base + j;
    int sl = (idx < end) ? __builtin_nontemporal_load(&srcp[idx]) : 0;
    int c = min(end - base, 64);
    int i = 0;
    for (; i + 4 <= c; i += 4) {
      int s0 = __builtin_amdgcn_readfirstlane(__shfl(sl, i));
      int s1 = __builtin_amdgcn_readfirstlane(__shfl(sl, i + 1));
      int s2 = __builtin_amdgcn_readfirstlane(__shfl(sl, i + 2));
      int s3 = __builtin_amdgcn_readfirstlane(__shfl(sl, i + 3));
      float h0 = bflo((uint)hinb[(size_t)s0 * 64 + j]);
      float h1 = bflo((uint)hinb[(size_t)s1 * 64 + j]);
      float h2v = bflo((uint)hinb[(size_t)s2 * 64 + j]);
      float h3 = bflo((uint)hinb[(size_t)s3 * 64 + j]);
      const uvec4* ep = (const uvec4*)(eapb + (size_t)(base + i) * 8);
      uvec4 E0 = __builtin_nontemporal_load(ep + 0);
      uvec4 E1 = __builtin_nontemporal_load(ep + 1);
      uvec4 E2 = __builtin_nontemporal_load(ep + 2);
      uvec4 E3 = __builtin_nontemporal_load(ep + 3);
      float a0[8], a1[8], a2[8], a3[8];
      ea8(E0, a0); ea8(E1, a1); ea8(E2, a2); ea8(E3, a3);
      float m0 = lbv + h0, m1 = lbv + h1, m2 = lbv + h2v, m3 = lbv + h3;
#pragma unroll
      for (int q = 0; q < 8; q++) {
        m0 = fmaf(a0[q], lwv[q], m0);
        m1 = fmaf(a1[q], lwv[q], m1);
        m2 = fmaf(a2[q], lwv[q], m2);
        m3 = fmaf(a3[q], lwv[q], m3);
      }
      acc += fmaxf(m0, 0.f) + fmaxf(m1, 0.f) + fmaxf(m2, 0.f) + fmaxf(m3, 0.f);
    }
    for (; i < c; i++) {
      int s = __builtin_amdgcn_readfirstlane(__shfl(sl, i));
      float hc = bflo((uint)hinb[(size_t)s * 64 + j]);
      uvec4 E = __builtin_nontemporal_load((const uvec4*)(eapb + (size_t)(base + i) * 8));
      float a[8];
      ea8(E, a);
      float m = lbv + hc;
#pragma unroll
      for (int q = 0; q < 8; q++) m = fmaf(a[q], lwv[q], m);
      acc += fmaxf(m, 0.f);
    }
  }
  float hv = __builtin_nontemporal_load(&hinf[(size_t)n * 64 + j]);
  float t = hv + acc;
  float q1 = b1[j];
  for (int k = 0; k < 64; k++) q1 = fmaf(__shfl(t, k), w1[k * 64 + j], q1);
  q1 = fmaxf(q1, 0.f);
  float h2 = b2[j];
  for (int k = 0; k < 64; k++) h2 = fmaf(__shfl(q1, k), w2[k * 64 + j], h2);
  h2 = fmaxf(h2, 0.f);
  float v = lane_layernorm(h2 + hv, lng[j], lnb[j]);
  if (houtf) houtf[(size_t)n * 64 + j] = v;
  houtbf[(size_t)n * 64 + j] = f2bf(v);
}

// ---------------------------------------------------------------------------
// Prep: dec_w1 (264x64, K zero-padded to 288) and dec_w2 (64x32) into per-lane
// bf16 B-fragments for mfma_f32_16x16x32_bf16.
__global__ __launch_bounds__(256) void prep_kernel(
    const float* __restrict__ w1, const float* __restrict__ w2,
    ushort* __restrict__ w1f, ushort* __restrict__ w2f) {
  int t = blockIdx.x * 256 + threadIdx.x;
  if (t < 18432) {
    int j = t & 7, lane = (t >> 3) & 63, f = t >> 9;
    int k = (f >> 2) * 32 + ((lane >> 4) * 8) + j;
    int n = (f & 3) * 16 + (lane & 15);
    float v = (k < 264) ? w1[k * 64 + n] : 0.f;
    w1f[t] = f2bf(v);
  } else {
    int t2 = t - 18432;
    int j = t2 & 7, lane = (t2 >> 3) & 63, f = t2 >> 9;
    int k = (f >> 1) * 32 + ((lane >> 4) * 8) + j;
    int n = (f & 1) * 16 + (lane & 15);
    w2f[t2] = f2bf(w2[k * 32 + n]);
  }
}

// ---------------------------------------------------------------------------
// MFMA decoder, CSR-ordered, ONE group per wave (GPW=1): minimal register
// footprint (no multi-group arrays -> no spills; R10/R11 lesson), 5x more
// independent waves chip-wide so gather latency is hidden by TLP not per-wave
// pipelining. Cached hb loads; nt only on stream-once srcp/dstp/eapb.
#define ZS 272
#define YS 72
#define NGRP 62500        // 1M edges / 16
#define NBLK 15625        // NGRP / 4 waves
#define BPX 1954          // ceil(NBLK/8); grid = 8*BPX = 15632

__global__ __launch_bounds__(256, 4) void decoder_kernel(
    const ushort* __restrict__ hb,
    const int* __restrict__ srcp, const int* __restrict__ dstp,
    const ushort* __restrict__ eapb,
    const ushort* __restrict__ w1f, const ushort* __restrict__ w2f,
    const float* __restrict__ b1, const float* __restrict__ b2,
    const float* __restrict__ w3, const float* __restrict__ b3,
    float* __restrict__ tmp) {
  __shared__ ushort zbuf[4][16 * ZS];     // 34816 B/block -> 4 blocks/CU
  const int w = threadIdx.x >> 6, l = threadIdx.x & 63;
  const int sub = l & 15, quad = l >> 4;
  int bb = (blockIdx.x & 7) * BPX + (blockIdx.x >> 3);
  if (bb >= NBLK) return;
  const int g = bb * 4 + w;               // group id, < 62500
  ushort* Z = zbuf[w];
  ushort* Y = Z;

  // issue gathers first (16 src + 16 dst rows + streams), then constants
  int s16 = __builtin_nontemporal_load(&srcp[g * 16 + sub]);
  int d16 = __builtin_nontemporal_load(&dstp[g * 16 + sub]);
  uvec2 pa[4], pb[4];
#pragma unroll
  for (int i = 0; i < 4; i++) {
    int s = __shfl(s16, 4 * i + quad), d = __shfl(d16, 4 * i + quad);
    pa[i] = *(const uvec2*)&hb[(size_t)s * 64 + sub * 4];
    pb[i] = *(const uvec2*)&hb[(size_t)d * 64 + sub * 4];
  }
  uint pe = __builtin_nontemporal_load((const uint*)eapb + (size_t)g * 64 + l);

  float b1v[4];
#pragma unroll
  for (int t = 0; t < 4; t++) b1v[t] = b1[t * 16 + sub];
  float b2v0 = b2[sub], b2v1 = b2[16 + sub];
  float w3v0 = w3[sub], w3v1 = w3[16 + sub];
  float b3v = b3[0];

  // ---- stage Z ----
#pragma unroll
  for (int i = 0; i < 4; i++) {
    int e = 4 * i + quad;
    uvec2 a = pa[i], b = pb[i];
    *(uvec2*)&Z[e * ZS + sub * 4] = a;
    *(uvec2*)&Z[e * ZS + 64 + sub * 4] = b;
    float a0 = bflo(a.x), a1 = bfhi(a.x), a2 = bflo(a.y), a3 = bfhi(a.y);
    float c0 = bflo(b.x), c1 = bfhi(b.x), c2 = bflo(b.y), c3 = bfhi(b.y);
    uvec2 u;
    u.x = pkbf(fabsf(a0 - c0), fabsf(a1 - c1));
    u.y = pkbf(fabsf(a2 - c2), fabsf(a3 - c3));
    *(uvec2*)&Z[e * ZS + 128 + sub * 4] = u;
    u.x = pkbf(a0 * c0, a1 * c1);
    u.y = pkbf(a2 * c2, a3 * c3);
    *(uvec2*)&Z[e * ZS + 192 + sub * 4] = u;
  }
  *(uint*)&Z[(l >> 2) * ZS + 256 + (l & 3) * 2] = pe;

  // ---- GEMM1: Z(16x264) @ W1(264x64) ----
  f32x4 acc[4];
#pragma unroll
  for (int t = 0; t < 4; t++) acc[t] = (f32x4){0.f, 0.f, 0.f, 0.f};
#pragma unroll
  for (int s = 0; s < 8; s++) {
    bf16x8 af = *(const bf16x8*)&Z[sub * ZS + s * 32 + quad * 8];
#pragma unroll
    for (int t = 0; t < 4; t++)
      acc[t] = __builtin_amdgcn_mfma_f32_16x16x32_bf16(
          af, ((const bf16x8*)w1f)[(s * 4 + t) * 64 + l], acc[t], 0, 0, 0);
  }
  {
    bf16x8 af8 = (bf16x8){0, 0, 0, 0, 0, 0, 0, 0};
    if (quad == 0) af8 = *(const bf16x8*)&Z[sub * ZS + 256];
#pragma unroll
    for (int t = 0; t < 4; t++)
      acc[t] = __builtin_amdgcn_mfma_f32_16x16x32_bf16(
          af8, ((const bf16x8*)w1f)[(32 + t) * 64 + l], acc[t], 0, 0, 0);
  }
#pragma unroll
  for (int t = 0; t < 4; t++)
#pragma unroll
    for (int r = 0; r < 4; r++)
      Y[(quad * 4 + r) * YS + t * 16 + sub] = f2bf(fmaxf(acc[t][r] + b1v[t], 0.f));

  // ---- GEMM2: Y1(16x64) @ W2(64x32) ----
  f32x4 acc2[2];
  acc2[0] = (f32x4){0.f, 0.f, 0.f, 0.f};
  acc2[1] = (f32x4){0.f, 0.f, 0.f, 0.f};
#pragma unroll
  for (int ks = 0; ks < 2; ks++) {
    union { bf16x8 v; ushort4 u[2]; } ya;
    int o = sub * YS + ks * 32 + quad * 8;
    ya.u[0] = *(const ushort4*)&Y[o];
    ya.u[1] = *(const ushort4*)&Y[o + 4];
    acc2[0] = __builtin_amdgcn_mfma_f32_16x16x32_bf16(
        ya.v, ((const bf16x8*)w2f)[(ks * 2 + 0) * 64 + l], acc2[0], 0, 0, 0);
    acc2[1] = __builtin_amdgcn_mfma_f32_16x16x32_bf16(
        ya.v, ((const bf16x8*)w2f)[(ks * 2 + 1) * 64 + l], acc2[1], 0, 0, 0);
  }
  // ---- relu, W3 dot, reduce; sequential store to tmp ----
#pragma unroll
  for (int r = 0; r < 4; r++) {
    float o = fmaxf(acc2[0][r] + b2v0, 0.f) * w3v0 +
              fmaxf(acc2[1][r] + b2v1, 0.f) * w3v1;
    o += __shfl_xor(o, 1);
    o += __shfl_xor(o, 2);
    o += __shfl_xor(o, 4);
    o += __shfl_xor(o, 8);
    if (sub == 0) tmp[g * 16 + quad * 4 + r] = o + b3v;
  }
}

// ---------------------------------------------------------------------------
extern "C" void kernel_launch(void* const* d_in, const int* in_sizes, int n_in,
                              void* d_out, int out_size, void* d_ws, size_t ws_size,
                              hipStream_t stream) {
  const float* x = (const float*)d_in[0];
  const int* ei = (const int*)d_in[1];
  const float* ea = (const float*)d_in[2];
  const float* l0_lin_w = (const float*)d_in[3];
  const float* l0_lin_b = (const float*)d_in[4];
  const float* l0_w1 = (const float*)d_in[5];
  const float* l0_b1 = (const float*)d_in[6];
  const float* l0_w2 = (const float*)d_in[7];
  const float* l0_b2 = (const float*)d_in[8];
  const float* l0_ln_g = (const float*)d_in[9];
  const float* l0_ln_b = (const float*)d_in[10];
  const float* l0_res_w = (const float*)d_in[11];
  const float* l0_res_b = (const float*)d_in[12];
  const float* dec_w1 = (const float*)d_in[29];
  const float* dec_b1 = (const float*)d_in[30];
  const float* dec_w2 = (const float*)d_in[31];
  const float* dec_b2 = (const float*)d_in[32];
  const float* dec_w3 = (const float*)d_in[33];
  const float* dec_b3 = (const float*)d_in[34];

  float* h_a = (float*)d_ws;                      // NN*64 f32
  float* h_b = h_a + (size_t)NN * 64;             // NN*64 f32
  ushort* hbA = (ushort*)(h_b + (size_t)NN * 64); // NN*64 bf16
  ushort* hbB = hbA + (size_t)NN * 64;            // NN*64 bf16
  int* ipos = (int*)(hbB + (size_t)NN * 64);      // NE
  int* srcp = ipos + NE;                          // NE
  int* dstp = srcp + NE;                          // NE
  float* tmp = (float*)(dstp + NE);               // NE f32 (sorted decoder out)
  int* off = (int*)(tmp + NE);                    // NN+1
  int* cnt = off + (NN + 1);                      // NN
  int* bsum = cnt + NN;                           // 256
  ushort* w1f = (ushort*)(bsum + 256);            // 18432 bf16
  ushort* w2f = w1f + 18432;                      // 2048 bf16
  ushort* eapb = w2f + 2048;                      // NE*8 bf16

  const int EB = (NE + 255) / 256;                // 3907
  const int SB = (NN + 256) / 256;                // 196

  // ---- CSR build ----
  hipMemsetAsync(cnt, 0, (size_t)NN * sizeof(int), stream);
  hist_kernel<<<EB, 256, 0, stream>>>(ei, cnt);
  scan1_kernel<<<SB, 256, 0, stream>>>(cnt, off, bsum);
  scan2_kernel<<<1, 256, 0, stream>>>(bsum, SB);
  scan3_kernel<<<SB, 256, 0, stream>>>(off, bsum, cnt);
  scatter_kernel<<<EB, 256, 0, stream>>>(ei, ea, off, cnt, ipos, srcp, dstp, eapb);

  // ---- fused GNN layers ----
  layer0_fused<<<NN / 4, 256, 0, stream>>>(x, h_a, hbA, eapb, srcp, off,
                                           l0_lin_w, l0_lin_b, l0_w1, l0_b1,
                                           l0_w2, l0_b2, l0_ln_g, l0_ln_b,
                                           l0_res_w, l0_res_b);
  layer_fused<<<NN / 4, 256, 0, stream>>>(hbA, h_a, h_b, hbB, eapb, srcp, off,
                                          (const float*)d_in[13], (const float*)d_in[14],
                                          (const float*)d_in[15], (const float*)d_in[16],
                                          (const float*)d_in[17], (const float*)d_in[18],
                                          (const float*)d_in[19], (const float*)d_in[20]);
  layer_fused<<<NN / 4, 256, 0, stream>>>(hbB, h_b, (float*)nullptr, hbA, eapb, srcp, off,
                                          (const float*)d_in[21], (const float*)d_in[22],
                                          (const float*)d_in[23], (const float*)d_in[24],
                                          (const float*)d_in[25], (const float*)d_in[26],
                                          (const float*)d_in[27], (const float*)d_in[28]);

  // ---- decoder ----
  prep_kernel<<<80, 256, 0, stream>>>(dec_w1, dec_w2, w1f, w2f);
  decoder_kernel<<<8 * BPX, 256, 0, stream>>>(hbA, srcp, dstp, eapb,
                                              w1f, w2f, dec_b1, dec_b2,
                                              dec_w3, dec_b3, tmp);
  unperm_kernel<<<EB, 256, 0, stream>>>(tmp, ipos, (float*)d_out);
}

// Round 13
// 679.921 us; speedup vs baseline: 1.2100x; 1.0311x over previous
//
#include <hip/hip_runtime.h>

#define NN 50000
#define NE 1000000

constexpr float LN_EPS = 1e-5f;

typedef short bf16x8 __attribute__((ext_vector_type(8)));
typedef float f32x4 __attribute__((ext_vector_type(4)));
typedef uint uvec4 __attribute__((ext_vector_type(4)));
typedef uint uvec2 __attribute__((ext_vector_type(2)));

// round-to-nearest-even float -> bf16
__device__ inline ushort f2bf(float x) {
  union { float f; uint u; } v; v.f = x;
  uint r = v.u + 0x7fffu + ((v.u >> 16) & 1u);
  return (ushort)(r >> 16);
}
__device__ inline uint pkbf(float a, float b) {
  union { float f; uint u; } x, y; x.f = a; y.f = b;
  uint ra = (x.u + 0x7fffu + ((x.u >> 16) & 1u)) >> 16;
  uint rb = (y.u + 0x7fffu + ((y.u >> 16) & 1u)) & 0xffff0000u;
  return ra | rb;
}
__device__ inline float bflo(uint u) { union { uint x; float f; } v; v.x = u << 16; return v.f; }
__device__ inline float bfhi(uint u) { union { uint x; float f; } v; v.x = u & 0xffff0000u; return v.f; }
__device__ inline void ea8(uvec4 E, float* o) {
  o[0] = bflo(E.x); o[1] = bfhi(E.x); o[2] = bflo(E.y); o[3] = bfhi(E.y);
  o[4] = bflo(E.z); o[5] = bfhi(E.z); o[6] = bflo(E.w); o[7] = bfhi(E.w);
}

// ---------------------------------------------------------------------------
// CSR build: histogram -> exclusive scan -> scatter.
__global__ __launch_bounds__(256) void hist_kernel(const int* __restrict__ ei,
                                                   int* __restrict__ cnt) {
  int e = blockIdx.x * 256 + threadIdx.x;
  if (e < NE) atomicAdd(&cnt[ei[NE + e]], 1);
}

__global__ __launch_bounds__(256) void scan1_kernel(const int* __restrict__ cnt,
                                                    int* __restrict__ off,
                                                    int* __restrict__ bsum) {
  __shared__ int sh[256];
  int t = threadIdx.x;
  int idx = blockIdx.x * 256 + t;
  int v = (idx < NN) ? cnt[idx] : 0;
  sh[t] = v;
  __syncthreads();
  for (int o = 1; o < 256; o <<= 1) {
    int xv = (t >= o) ? sh[t - o] : 0;
    __syncthreads();
    sh[t] += xv;
    __syncthreads();
  }
  if (idx <= NN) off[idx] = sh[t] - v;
  if (t == 255) bsum[blockIdx.x] = sh[255];
}

__global__ __launch_bounds__(256) void scan2_kernel(int* __restrict__ bsum, int nb) {
  __shared__ int sh[256];
  int t = threadIdx.x;
  int v = (t < nb) ? bsum[t] : 0;
  sh[t] = v;
  __syncthreads();
  for (int o = 1; o < 256; o <<= 1) {
    int xv = (t >= o) ? sh[t - o] : 0;
    __syncthreads();
    sh[t] += xv;
    __syncthreads();
  }
  if (t < nb) bsum[t] = sh[t] - v;
}

__global__ __launch_bounds__(256) void scan3_kernel(int* __restrict__ off,
                                                    const int* __restrict__ bsum,
                                                    int* __restrict__ cnt) {
  int idx = blockIdx.x * 256 + threadIdx.x;
  if (idx <= NN) off[idx] += bsum[blockIdx.x];
  if (idx < NN) cnt[idx] = 0;
}

// scatter emits: srcp/dstp (sorted endpoint ids), eapb (dst-sorted bf16 edge
// attrs), ipos (edge -> sorted position inverse map, coalesced by e).
__global__ __launch_bounds__(256) void scatter_kernel(
    const int* __restrict__ ei, const float* __restrict__ ea,
    const int* __restrict__ off, int* __restrict__ cur,
    int* __restrict__ ipos, int* __restrict__ srcp, int* __restrict__ dstp,
    ushort* __restrict__ eapb) {
  int e = blockIdx.x * 256 + threadIdx.x;
  if (e < NE) {
    int d = ei[NE + e];
    int s = ei[e];
    int p = off[d] + atomicAdd(&cur[d], 1);
    ipos[e] = p;
    srcp[p] = s;
    dstp[p] = d;
    const float* eaf = ea + (size_t)e * 8;
    uvec4 u;
    u.x = pkbf(eaf[0], eaf[1]);
    u.y = pkbf(eaf[2], eaf[3]);
    u.z = pkbf(eaf[4], eaf[5]);
    u.w = pkbf(eaf[6], eaf[7]);
    __builtin_nontemporal_store(u, (uvec4*)(eapb + (size_t)p * 8));
  }
}

// unpermute: coalesced write of out, random 4B read of the 4MB tmp table.
__global__ __launch_bounds__(256) void unperm_kernel(const float* __restrict__ tmp,
                                                     const int* __restrict__ ipos,
                                                     float* __restrict__ out) {
  int e = blockIdx.x * 256 + threadIdx.x;
  if (e < NE) out[e] = tmp[ipos[e]];
}

// ---------------------------------------------------------------------------
__device__ inline float lane_layernorm(float r, float g, float b) {
  float s = r;
#pragma unroll
  for (int m = 32; m >= 1; m >>= 1) s += __shfl_xor(s, m);
  float mu = s * (1.f / 64.f);
  float dv = r - mu;
  float v = dv * dv;
#pragma unroll
  for (int m = 32; m >= 1; m >>= 1) v += __shfl_xor(v, m);
  float var = v * (1.f / 64.f);
  return dv * rsqrtf(var + LN_EPS) * g + b;
}

// ---------------------------------------------------------------------------
// Fused layer 0 (D=16): aggregation + MLP + residual Linear + LN.
__global__ __launch_bounds__(256) void layer0_fused(
    const float* __restrict__ x, float* __restrict__ hout,
    ushort* __restrict__ houtbf,
    const ushort* __restrict__ eapb, const int* __restrict__ srcp,
    const int* __restrict__ off,
    const float* __restrict__ lw, const float* __restrict__ lb,
    const float* __restrict__ w1, const float* __restrict__ b1,
    const float* __restrict__ w2, const float* __restrict__ b2,
    const float* __restrict__ lng, const float* __restrict__ lnb,
    const float* __restrict__ rw, const float* __restrict__ rb) {
  int n = blockIdx.x * 4 + (threadIdx.x >> 6);
  int j = threadIdx.x & 63;
  int d = j & 15, slot = j >> 4;
  int start = off[n], end = off[n + 1];
  float lwv[8];
#pragma unroll
  for (int i = 0; i < 8; i++) lwv[i] = lw[i * 16 + d];
  float lbv = lb[d];
  float acc = 0.f;
  for (int base = start; base < end; base += 64) {
    int idx = base + j;
    int sl = (idx < end) ? srcp[idx] : 0;
    int c = min(end - base, 64);
    for (int i0 = 0; i0 < c; i0 += 4) {
      int i = i0 + slot;
      bool valid = i < c;
      int ii = i & 63;
      int s = __shfl(sl, ii);
      int pp = min(base + i0 + slot, NE - 1);
      float ev = bflo((uint)eapb[(size_t)pp * 8 + (d & 7)]);
      float xs = x[(size_t)s * 16 + d];
      float m = lbv + xs;
#pragma unroll
      for (int q = 0; q < 8; q++) m = fmaf(__shfl(ev, slot * 16 + q), lwv[q], m);
      m = fmaxf(m, 0.f);
      acc += valid ? m : 0.f;
    }
  }
  acc += __shfl_xor(acc, 16);
  acc += __shfl_xor(acc, 32);
  float xr = x[(size_t)n * 16 + d];
  float t = xr + acc;
  float q1 = b1[j];
#pragma unroll 4
  for (int k = 0; k < 16; k++) q1 = fmaf(__shfl(t, k), w1[k * 64 + j], q1);
  q1 = fmaxf(q1, 0.f);
  float h2 = b2[j];
  for (int k = 0; k < 64; k++) h2 = fmaf(__shfl(q1, k), w2[k * 64 + j], h2);
  h2 = fmaxf(h2, 0.f);
  float res = rb[j];
#pragma unroll 4
  for (int k = 0; k < 16; k++) res = fmaf(__shfl(xr, k), rw[k * 64 + j], res);
  float v = lane_layernorm(h2 + res, lng[j], lnb[j]);
  hout[(size_t)n * 64 + j] = v;
  houtbf[(size_t)n * 64 + j] = f2bf(v);
}

// ---------------------------------------------------------------------------
// Fused layers 1/2 (D=64): bf16 h gathers; eapb/srcp/hinf consumed once ->
// nt loads so the hinb gather table stays L2-resident.
__global__ __launch_bounds__(256) void layer_fused(
    const ushort* __restrict__ hinb, const float* __restrict__ hinf,
    float* __restrict__ houtf, ushort* __restrict__ houtbf,
    const ushort* __restrict__ eapb, const int* __restrict__ srcp,
    const int* __restrict__ off,
    const float* __restrict__ lw, const float* __restrict__ lb,
    const float* __restrict__ w1, const float* __restrict__ b1,
    const float* __restrict__ w2, const float* __restrict__ b2,
    const float* __restrict__ lng, const float* __restrict__ lnb) {
  int n = blockIdx.x * 4 + (threadIdx.x >> 6);
  int j = threadIdx.x & 63;
  int start = off[n], end = off[n + 1];
  float lwv[8];
#pragma unroll
  for (int i = 0; i < 8; i++) lwv[i] = lw[i * 64 + j];
  float lbv = lb[j];
  float acc = 0.f;
  for (int base = start; base < end; base += 64) {
    int idx = base + j;
    int sl = (idx < end) ? __builtin_nontemporal_load(&srcp[idx]) : 0;
    int c = min(end - base, 64);
    int i = 0;
    for (; i + 4 <= c; i += 4) {
      int s0 = __builtin_amdgcn_readfirstlane(__shfl(sl, i));
      int s1 = __builtin_amdgcn_readfirstlane(__shfl(sl, i + 1));
      int s2 = __builtin_amdgcn_readfirstlane(__shfl(sl, i + 2));
      int s3 = __builtin_amdgcn_readfirstlane(__shfl(sl, i + 3));
      float h0 = bflo((uint)hinb[(size_t)s0 * 64 + j]);
      float h1 = bflo((uint)hinb[(size_t)s1 * 64 + j]);
      float h2v = bflo((uint)hinb[(size_t)s2 * 64 + j]);
      float h3 = bflo((uint)hinb[(size_t)s3 * 64 + j]);
      const uvec4* ep = (const uvec4*)(eapb + (size_t)(base + i) * 8);
      uvec4 E0 = __builtin_nontemporal_load(ep + 0);
      uvec4 E1 = __builtin_nontemporal_load(ep + 1);
      uvec4 E2 = __builtin_nontemporal_load(ep + 2);
      uvec4 E3 = __builtin_nontemporal_load(ep + 3);
      float a0[8], a1[8], a2[8], a3[8];
      ea8(E0, a0); ea8(E1, a1); ea8(E2, a2); ea8(E3, a3);
      float m0 = lbv + h0, m1 = lbv + h1, m2 = lbv + h2v, m3 = lbv + h3;
#pragma unroll
      for (int q = 0; q < 8; q++) {
        m0 = fmaf(a0[q], lwv[q], m0);
        m1 = fmaf(a1[q], lwv[q], m1);
        m2 = fmaf(a2[q], lwv[q], m2);
        m3 = fmaf(a3[q], lwv[q], m3);
      }
      acc += fmaxf(m0, 0.f) + fmaxf(m1, 0.f) + fmaxf(m2, 0.f) + fmaxf(m3, 0.f);
    }
    for (; i < c; i++) {
      int s = __builtin_amdgcn_readfirstlane(__shfl(sl, i));
      float hc = bflo((uint)hinb[(size_t)s * 64 + j]);
      uvec4 E = __builtin_nontemporal_load((const uvec4*)(eapb + (size_t)(base + i) * 8));
      float a[8];
      ea8(E, a);
      float m = lbv + hc;
#pragma unroll
      for (int q = 0; q < 8; q++) m = fmaf(a[q], lwv[q], m);
      acc += fmaxf(m, 0.f);
    }
  }
  float hv = __builtin_nontemporal_load(&hinf[(size_t)n * 64 + j]);
  float t = hv + acc;
  float q1 = b1[j];
  for (int k = 0; k < 64; k++) q1 = fmaf(__shfl(t, k), w1[k * 64 + j], q1);
  q1 = fmaxf(q1, 0.f);
  float h2 = b2[j];
  for (int k = 0; k < 64; k++) h2 = fmaf(__shfl(q1, k), w2[k * 64 + j], h2);
  h2 = fmaxf(h2, 0.f);
  float v = lane_layernorm(h2 + hv, lng[j], lnb[j]);
  if (houtf) houtf[(size_t)n * 64 + j] = v;
  houtbf[(size_t)n * 64 + j] = f2bf(v);
}

// ---------------------------------------------------------------------------
// Prep: dec_w1 (264x64, K zero-padded to 288) and dec_w2 (64x32) into per-lane
// bf16 B-fragments for mfma_f32_16x16x32_bf16.
__global__ __launch_bounds__(256) void prep_kernel(
    const float* __restrict__ w1, const float* __restrict__ w2,
    ushort* __restrict__ w1f, ushort* __restrict__ w2f) {
  int t = blockIdx.x * 256 + threadIdx.x;
  if (t < 18432) {
    int j = t & 7, lane = (t >> 3) & 63, f = t >> 9;
    int k = (f >> 2) * 32 + ((lane >> 4) * 8) + j;
    int n = (f & 3) * 16 + (lane & 15);
    float v = (k < 264) ? w1[k * 64 + n] : 0.f;
    w1f[t] = f2bf(v);
  } else {
    int t2 = t - 18432;
    int j = t2 & 7, lane = (t2 >> 3) & 63, f = t2 >> 9;
    int k = (f >> 1) * 32 + ((lane >> 4) * 8) + j;
    int n = (f & 1) * 16 + (lane & 15);
    w2f[t2] = f2bf(w2[k * 32 + n]);
  }
}

// ---------------------------------------------------------------------------
// MFMA decoder, CSR-ordered, M=32 per wave: one wave stages 32 edges as TWO
// 16-row A-tiles that SHARE each W1 B-fragment load -> w1f L2 traffic halves
// (the R12 hidden cost: 36KB/wave of B-frags re-read from L2). 128-thread
// blocks (2 waves, 34.8KB LDS) -> 4 blocks/CU, 8 waves/CU, no spills.
#define ZS 272
#define YS 72
#define NGRP 31250         // 1M edges / 32
#define NBLK 15625         // NGRP / 2 waves per block
#define BPX 1954           // ceil(NBLK/8); grid = 8*BPX = 15632

__global__ __launch_bounds__(128, 2) void decoder_kernel(
    const ushort* __restrict__ hb,
    const int* __restrict__ srcp, const int* __restrict__ dstp,
    const ushort* __restrict__ eapb,
    const ushort* __restrict__ w1f, const ushort* __restrict__ w2f,
    const float* __restrict__ b1, const float* __restrict__ b2,
    const float* __restrict__ w3, const float* __restrict__ b3,
    float* __restrict__ tmp) {
  __shared__ ushort zbuf[2][32 * ZS];     // 34816 B/block -> 4 blocks/CU
  const int w = threadIdx.x >> 6, l = threadIdx.x & 63;
  const int sub = l & 15, quad = l >> 4;
  int bb = (blockIdx.x & 7) * BPX + (blockIdx.x >> 3);
  if (bb >= NBLK) return;
  const int g = bb * 2 + w;               // group id, < 31250
  ushort* Z = zbuf[w];
  ushort* Y = Z;                          // overlay (32 x YS fits in Z)

  // issue gathers first: 32 src + 32 dst rows (16 load instrs in flight)
  int s32 = __builtin_nontemporal_load(&srcp[g * 32 + (l & 31)]);
  int d32 = __builtin_nontemporal_load(&dstp[g * 32 + (l & 31)]);
  uvec2 pa[8], pb[8];
#pragma unroll
  for (int i = 0; i < 8; i++) {
    int e = 4 * i + quad;                 // 0..31
    int s = __shfl(s32, e), d = __shfl(d32, e);
    pa[i] = *(const uvec2*)&hb[(size_t)s * 64 + sub * 4];
    pb[i] = *(const uvec2*)&hb[(size_t)d * 64 + sub * 4];
  }
  // edge attrs: lane l covers edge l>>1, half l&1 (8B = 4 bf16 cols)
  uvec2 pe = __builtin_nontemporal_load((const uvec2*)eapb + (size_t)g * 64 + l);

  float b1v[4];
#pragma unroll
  for (int t = 0; t < 4; t++) b1v[t] = b1[t * 16 + sub];
  float b2v0 = b2[sub], b2v1 = b2[16 + sub];
  float w3v0 = w3[sub], w3v1 = w3[16 + sub];
  float b3v = b3[0];

  // ---- stage Z (32 rows x 264 cols) ----
#pragma unroll
  for (int i = 0; i < 8; i++) {
    int e = 4 * i + quad;
    uvec2 a = pa[i], b = pb[i];
    *(uvec2*)&Z[e * ZS + sub * 4] = a;
    *(uvec2*)&Z[e * ZS + 64 + sub * 4] = b;
    float a0 = bflo(a.x), a1 = bfhi(a.x), a2 = bflo(a.y), a3 = bfhi(a.y);
    float c0 = bflo(b.x), c1 = bfhi(b.x), c2 = bflo(b.y), c3 = bfhi(b.y);
    uvec2 u;
    u.x = pkbf(fabsf(a0 - c0), fabsf(a1 - c1));
    u.y = pkbf(fabsf(a2 - c2), fabsf(a3 - c3));
    *(uvec2*)&Z[e * ZS + 128 + sub * 4] = u;
    u.x = pkbf(a0 * c0, a1 * c1);
    u.y = pkbf(a2 * c2, a3 * c3);
    *(uvec2*)&Z[e * ZS + 192 + sub * 4] = u;
  }
  *(uvec2*)&Z[(l >> 1) * ZS + 256 + (l & 1) * 4] = pe;

  // ---- GEMM1: Z(32x264) @ W1(264x64); B-frag shared by both 16-row tiles ----
  f32x4 acc[2][4];
#pragma unroll
  for (int m = 0; m < 2; m++)
#pragma unroll
    for (int t = 0; t < 4; t++) acc[m][t] = (f32x4){0.f, 0.f, 0.f, 0.f};
#pragma unroll
  for (int s = 0; s < 8; s++) {
    bf16x8 afA = *(const bf16x8*)&Z[sub * ZS + s * 32 + quad * 8];
    bf16x8 afB = *(const bf16x8*)&Z[(16 + sub) * ZS + s * 32 + quad * 8];
#pragma unroll
    for (int t = 0; t < 4; t++) {
      bf16x8 bf = ((const bf16x8*)w1f)[(s * 4 + t) * 64 + l];
      acc[0][t] = __builtin_amdgcn_mfma_f32_16x16x32_bf16(afA, bf, acc[0][t], 0, 0, 0);
      acc[1][t] = __builtin_amdgcn_mfma_f32_16x16x32_bf16(afB, bf, acc[1][t], 0, 0, 0);
    }
  }
  {  // tail kstep s=8: quads 1..3 carry k>=264 -> zero A in regs
    bf16x8 afA = (bf16x8){0, 0, 0, 0, 0, 0, 0, 0};
    bf16x8 afB = (bf16x8){0, 0, 0, 0, 0, 0, 0, 0};
    if (quad == 0) {
      afA = *(const bf16x8*)&Z[sub * ZS + 256];
      afB = *(const bf16x8*)&Z[(16 + sub) * ZS + 256];
    }
#pragma unroll
    for (int t = 0; t < 4; t++) {
      bf16x8 bf = ((const bf16x8*)w1f)[(32 + t) * 64 + l];
      acc[0][t] = __builtin_amdgcn_mfma_f32_16x16x32_bf16(afA, bf, acc[0][t], 0, 0, 0);
      acc[1][t] = __builtin_amdgcn_mfma_f32_16x16x32_bf16(afB, bf, acc[1][t], 0, 0, 0);
    }
  }
  // ---- relu + bf16 -> Y1 overlay (32 x 64) ----
#pragma unroll
  for (int m = 0; m < 2; m++)
#pragma unroll
    for (int t = 0; t < 4; t++)
#pragma unroll
      for (int r = 0; r < 4; r++)
        Y[(m * 16 + quad * 4 + r) * YS + t * 16 + sub] =
            f2bf(fmaxf(acc[m][t][r] + b1v[t], 0.f));

  // ---- GEMM2: Y1(32x64) @ W2(64x32); w2f frags loaded once ----
  bf16x8 w2frag[4];
#pragma unroll
  for (int f = 0; f < 4; f++) w2frag[f] = ((const bf16x8*)w2f)[f * 64 + l];
  f32x4 acc2[2][2];
#pragma unroll
  for (int m = 0; m < 2; m++) {
    acc2[m][0] = (f32x4){0.f, 0.f, 0.f, 0.f};
    acc2[m][1] = (f32x4){0.f, 0.f, 0.f, 0.f};
#pragma unroll
    for (int ks = 0; ks < 2; ks++) {
      union { bf16x8 v; ushort4 u[2]; } ya;
      int o = (m * 16 + sub) * YS + ks * 32 + quad * 8;
      ya.u[0] = *(const ushort4*)&Y[o];
      ya.u[1] = *(const ushort4*)&Y[o + 4];
      acc2[m][0] = __builtin_amdgcn_mfma_f32_16x16x32_bf16(ya.v, w2frag[ks * 2 + 0],
                                                           acc2[m][0], 0, 0, 0);
      acc2[m][1] = __builtin_amdgcn_mfma_f32_16x16x32_bf16(ya.v, w2frag[ks * 2 + 1],
                                                           acc2[m][1], 0, 0, 0);
    }
  }
  // ---- relu, W3 dot, reduce; sequential store to tmp ----
#pragma unroll
  for (int m = 0; m < 2; m++)
#pragma unroll
    for (int r = 0; r < 4; r++) {
      float o = fmaxf(acc2[m][0][r] + b2v0, 0.f) * w3v0 +
                fmaxf(acc2[m][1][r] + b2v1, 0.f) * w3v1;
      o += __shfl_xor(o, 1);
      o += __shfl_xor(o, 2);
      o += __shfl_xor(o, 4);
      o += __shfl_xor(o, 8);
      if (sub == 0) tmp[g * 32 + m * 16 + quad * 4 + r] = o + b3v;
    }
}

// ---------------------------------------------------------------------------
extern "C" void kernel_launch(void* const* d_in, const int* in_sizes, int n_in,
                              void* d_out, int out_size, void* d_ws, size_t ws_size,
                              hipStream_t stream) {
  const float* x = (const float*)d_in[0];
  const int* ei = (const int*)d_in[1];
  const float* ea = (const float*)d_in[2];
  const float* l0_lin_w = (const float*)d_in[3];
  const float* l0_lin_b = (const float*)d_in[4];
  const float* l0_w1 = (const float*)d_in[5];
  const float* l0_b1 = (const float*)d_in[6];
  const float* l0_w2 = (const float*)d_in[7];
  const float* l0_b2 = (const float*)d_in[8];
  const float* l0_ln_g = (const float*)d_in[9];
  const float* l0_ln_b = (const float*)d_in[10];
  const float* l0_res_w = (const float*)d_in[11];
  const float* l0_res_b = (const float*)d_in[12];
  const float* dec_w1 = (const float*)d_in[29];
  const float* dec_b1 = (const float*)d_in[30];
  const float* dec_w2 = (const float*)d_in[31];
  const float* dec_b2 = (const float*)d_in[32];
  const float* dec_w3 = (const float*)d_in[33];
  const float* dec_b3 = (const float*)d_in[34];

  float* h_a = (float*)d_ws;                      // NN*64 f32
  float* h_b = h_a + (size_t)NN * 64;             // NN*64 f32
  ushort* hbA = (ushort*)(h_b + (size_t)NN * 64); // NN*64 bf16
  ushort* hbB = hbA + (size_t)NN * 64;            // NN*64 bf16
  int* ipos = (int*)(hbB + (size_t)NN * 64);      // NE
  int* srcp = ipos + NE;                          // NE
  int* dstp = srcp + NE;                          // NE
  float* tmp = (float*)(dstp + NE);               // NE f32 (sorted decoder out)
  int* off = (int*)(tmp + NE);                    // NN+1
  int* cnt = off + (NN + 1);                      // NN
  int* bsum = cnt + NN;                           // 256
  ushort* w1f = (ushort*)(bsum + 256);            // 18432 bf16
  ushort* w2f = w1f + 18432;                      // 2048 bf16
  ushort* eapb = w2f + 2048;                      // NE*8 bf16

  const int EB = (NE + 255) / 256;                // 3907
  const int SB = (NN + 256) / 256;                // 196

  // ---- CSR build ----
  hipMemsetAsync(cnt, 0, (size_t)NN * sizeof(int), stream);
  hist_kernel<<<EB, 256, 0, stream>>>(ei, cnt);
  scan1_kernel<<<SB, 256, 0, stream>>>(cnt, off, bsum);
  scan2_kernel<<<1, 256, 0, stream>>>(bsum, SB);
  scan3_kernel<<<SB, 256, 0, stream>>>(off, bsum, cnt);
  scatter_kernel<<<EB, 256, 0, stream>>>(ei, ea, off, cnt, ipos, srcp, dstp, eapb);

  // ---- fused GNN layers ----
  layer0_fused<<<NN / 4, 256, 0, stream>>>(x, h_a, hbA, eapb, srcp, off,
                                           l0_lin_w, l0_lin_b, l0_w1, l0_b1,
                                           l0_w2, l0_b2, l0_ln_g, l0_ln_b,
                                           l0_res_w, l0_res_b);
  layer_fused<<<NN / 4, 256, 0, stream>>>(hbA, h_a, h_b, hbB, eapb, srcp, off,
                                          (const float*)d_in[13], (const float*)d_in[14],
                                          (const float*)d_in[15], (const float*)d_in[16],
                                          (const float*)d_in[17], (const float*)d_in[18],
                                          (const float*)d_in[19], (const float*)d_in[20]);
  layer_fused<<<NN / 4, 256, 0, stream>>>(hbB, h_b, (float*)nullptr, hbA, eapb, srcp, off,
                                          (const float*)d_in[21], (const float*)d_in[22],
                                          (const float*)d_in[23], (const float*)d_in[24],
                                          (const float*)d_in[25], (const float*)d_in[26],
                                          (const float*)d_in[27], (const float*)d_in[28]);

  // ---- decoder ----
  prep_kernel<<<80, 256, 0, stream>>>(dec_w1, dec_w2, w1f, w2f);
  decoder_kernel<<<8 * BPX, 128, 0, stream>>>(hbA, srcp, dstp, eapb,
                                              w1f, w2f, dec_b1, dec_b2,
                                              dec_w3, dec_b3, tmp);
  unperm_kernel<<<EB, 256, 0, stream>>>(tmp, ipos, (float*)d_out);
}

// Round 14
// 644.173 us; speedup vs baseline: 1.2771x; 1.0555x over previous
//
#include <hip/hip_runtime.h>

#define NN 50000
#define NE 1000000

constexpr float LN_EPS = 1e-5f;

typedef short bf16x8 __attribute__((ext_vector_type(8)));
typedef float f32x4 __attribute__((ext_vector_type(4)));
typedef uint uvec4 __attribute__((ext_vector_type(4)));
typedef uint uvec2 __attribute__((ext_vector_type(2)));

// round-to-nearest-even float -> bf16
__device__ inline ushort f2bf(float x) {
  union { float f; uint u; } v; v.f = x;
  uint r = v.u + 0x7fffu + ((v.u >> 16) & 1u);
  return (ushort)(r >> 16);
}
__device__ inline uint pkbf(float a, float b) {
  union { float f; uint u; } x, y; x.f = a; y.f = b;
  uint ra = (x.u + 0x7fffu + ((x.u >> 16) & 1u)) >> 16;
  uint rb = (y.u + 0x7fffu + ((y.u >> 16) & 1u)) & 0xffff0000u;
  return ra | rb;
}
__device__ inline float bflo(uint u) { union { uint x; float f; } v; v.x = u << 16; return v.f; }
__device__ inline float bfhi(uint u) { union { uint x; float f; } v; v.x = u & 0xffff0000u; return v.f; }

// ---------------------------------------------------------------------------
// CSR build: histogram -> exclusive scan -> scatter.
__global__ __launch_bounds__(256) void hist_kernel(const int* __restrict__ ei,
                                                   int* __restrict__ cnt) {
  int e = blockIdx.x * 256 + threadIdx.x;
  if (e < NE) atomicAdd(&cnt[ei[NE + e]], 1);
}

__global__ __launch_bounds__(256) void scan1_kernel(const int* __restrict__ cnt,
                                                    int* __restrict__ off,
                                                    int* __restrict__ bsum) {
  __shared__ int sh[256];
  int t = threadIdx.x;
  int idx = blockIdx.x * 256 + t;
  int v = (idx < NN) ? cnt[idx] : 0;
  sh[t] = v;
  __syncthreads();
  for (int o = 1; o < 256; o <<= 1) {
    int xv = (t >= o) ? sh[t - o] : 0;
    __syncthreads();
    sh[t] += xv;
    __syncthreads();
  }
  if (idx <= NN) off[idx] = sh[t] - v;
  if (t == 255) bsum[blockIdx.x] = sh[255];
}

__global__ __launch_bounds__(256) void scan2_kernel(int* __restrict__ bsum, int nb) {
  __shared__ int sh[256];
  int t = threadIdx.x;
  int v = (t < nb) ? bsum[t] : 0;
  sh[t] = v;
  __syncthreads();
  for (int o = 1; o < 256; o <<= 1) {
    int xv = (t >= o) ? sh[t - o] : 0;
    __syncthreads();
    sh[t] += xv;
    __syncthreads();
  }
  if (t < nb) bsum[t] = sh[t] - v;
}

__global__ __launch_bounds__(256) void scan3_kernel(int* __restrict__ off,
                                                    const int* __restrict__ bsum,
                                                    int* __restrict__ cnt) {
  int idx = blockIdx.x * 256 + threadIdx.x;
  if (idx <= NN) off[idx] += bsum[blockIdx.x];
  if (idx < NN) cnt[idx] = 0;
}

// scatter emits: srcp/dstp (sorted endpoint ids), eapb (dst-sorted bf16 edge
// attrs), ipos (edge -> sorted position inverse map, coalesced by e).
__global__ __launch_bounds__(256) void scatter_kernel(
    const int* __restrict__ ei, const float* __restrict__ ea,
    const int* __restrict__ off, int* __restrict__ cur,
    int* __restrict__ ipos, int* __restrict__ srcp, int* __restrict__ dstp,
    ushort* __restrict__ eapb) {
  int e = blockIdx.x * 256 + threadIdx.x;
  if (e < NE) {
    int d = ei[NE + e];
    int s = ei[e];
    int p = off[d] + atomicAdd(&cur[d], 1);
    ipos[e] = p;
    srcp[p] = s;
    dstp[p] = d;
    const float* eaf = ea + (size_t)e * 8;
    uvec4 u;
    u.x = pkbf(eaf[0], eaf[1]);
    u.y = pkbf(eaf[2], eaf[3]);
    u.z = pkbf(eaf[4], eaf[5]);
    u.w = pkbf(eaf[6], eaf[7]);
    __builtin_nontemporal_store(u, (uvec4*)(eapb + (size_t)p * 8));
  }
}

// unpermute: coalesced write of out, random 4B read of the 4MB tmp table.
__global__ __launch_bounds__(256) void unperm_kernel(const float* __restrict__ tmp,
                                                     const int* __restrict__ ipos,
                                                     float* __restrict__ out) {
  int e = blockIdx.x * 256 + threadIdx.x;
  if (e < NE) out[e] = tmp[ipos[e]];
}

// ---------------------------------------------------------------------------
__device__ inline float lane_layernorm(float r, float g, float b) {
  float s = r;
#pragma unroll
  for (int m = 32; m >= 1; m >>= 1) s += __shfl_xor(s, m);
  float mu = s * (1.f / 64.f);
  float dv = r - mu;
  float v = dv * dv;
#pragma unroll
  for (int m = 32; m >= 1; m >>= 1) v += __shfl_xor(v, m);
  float var = v * (1.f / 64.f);
  return dv * rsqrtf(var + LN_EPS) * g + b;
}

// ---------------------------------------------------------------------------
// Fused layer 0 (D=16): aggregation + MLP + residual Linear + LN.
__global__ __launch_bounds__(256) void layer0_fused(
    const float* __restrict__ x, float* __restrict__ hout,
    ushort* __restrict__ houtbf,
    const ushort* __restrict__ eapb, const int* __restrict__ srcp,
    const int* __restrict__ off,
    const float* __restrict__ lw, const float* __restrict__ lb,
    const float* __restrict__ w1, const float* __restrict__ b1,
    const float* __restrict__ w2, const float* __restrict__ b2,
    const float* __restrict__ lng, const float* __restrict__ lnb,
    const float* __restrict__ rw, const float* __restrict__ rb) {
  int n = blockIdx.x * 4 + (threadIdx.x >> 6);
  int j = threadIdx.x & 63;
  int d = j & 15, slot = j >> 4;
  int start = off[n], end = off[n + 1];
  float lwv[8];
#pragma unroll
  for (int i = 0; i < 8; i++) lwv[i] = lw[i * 16 + d];
  float lbv = lb[d];
  float acc = 0.f;
  for (int base = start; base < end; base += 64) {
    int idx = base + j;
    int sl = (idx < end) ? srcp[idx] : 0;
    int c = min(end - base, 64);
    for (int i0 = 0; i0 < c; i0 += 4) {
      int i = i0 + slot;
      bool valid = i < c;
      int ii = i & 63;
      int s = __shfl(sl, ii);
      int pp = min(base + i0 + slot, NE - 1);
      float ev = bflo((uint)eapb[(size_t)pp * 8 + (d & 7)]);
      float xs = x[(size_t)s * 16 + d];
      float m = lbv + xs;
#pragma unroll
      for (int q = 0; q < 8; q++) m = fmaf(__shfl(ev, slot * 16 + q), lwv[q], m);
      m = fmaxf(m, 0.f);
      acc += valid ? m : 0.f;
    }
  }
  acc += __shfl_xor(acc, 16);
  acc += __shfl_xor(acc, 32);
  float xr = x[(size_t)n * 16 + d];
  float t = xr + acc;
  float q1 = b1[j];
#pragma unroll 4
  for (int k = 0; k < 16; k++) q1 = fmaf(__shfl(t, k), w1[k * 64 + j], q1);
  q1 = fmaxf(q1, 0.f);
  float h2 = b2[j];
  for (int k = 0; k < 64; k++) h2 = fmaf(__shfl(q1, k), w2[k * 64 + j], h2);
  h2 = fmaxf(h2, 0.f);
  float res = rb[j];
#pragma unroll 4
  for (int k = 0; k < 16; k++) res = fmaf(__shfl(xr, k), rw[k * 64 + j], res);
  float v = lane_layernorm(h2 + res, lng[j], lnb[j]);
  hout[(size_t)n * 64 + j] = v;
  houtbf[(size_t)n * 64 + j] = f2bf(v);
}

// ---------------------------------------------------------------------------
// Fused layers 1/2 (D=64), shfl-free aggregation: per-edge src ids and edge
// attrs are wave-uniform -> broadcast loads + readfirstlane into SGPRs; bf16
// unpack becomes SALU (s_lshl/s_and) feeding v_fma SGPR operands. 8 gathers
// in flight per block. eapb/srcp/hinf consumed once -> nt loads.
__device__ inline float edge8_msg(const ushort* __restrict__ hinb, int s, int j,
                                  uint ulo, uint uhi, uint vlo, uint vhi,
                                  const float* lwv, float lbv) {
  float hc = bflo((uint)hinb[(size_t)s * 64 + j]);
  float m = lbv + hc;
  m = fmaf(bflo(ulo), lwv[0], m);
  m = fmaf(bfhi(ulo), lwv[1], m);
  m = fmaf(bflo(uhi), lwv[2], m);
  m = fmaf(bfhi(uhi), lwv[3], m);
  m = fmaf(bflo(vlo), lwv[4], m);
  m = fmaf(bfhi(vlo), lwv[5], m);
  m = fmaf(bflo(vhi), lwv[6], m);
  m = fmaf(bfhi(vhi), lwv[7], m);
  return fmaxf(m, 0.f);
}

__global__ __launch_bounds__(256) void layer_fused(
    const ushort* __restrict__ hinb, const float* __restrict__ hinf,
    float* __restrict__ houtf, ushort* __restrict__ houtbf,
    const ushort* __restrict__ eapb, const int* __restrict__ srcp,
    const int* __restrict__ off,
    const float* __restrict__ lw, const float* __restrict__ lb,
    const float* __restrict__ w1, const float* __restrict__ b1,
    const float* __restrict__ w2, const float* __restrict__ b2,
    const float* __restrict__ lng, const float* __restrict__ lnb) {
  int n = blockIdx.x * 4 + (threadIdx.x >> 6);
  int j = threadIdx.x & 63;
  int start = __builtin_amdgcn_readfirstlane(off[n]);
  int end = __builtin_amdgcn_readfirstlane(off[n + 1]);
  float lwv[8];
#pragma unroll
  for (int i = 0; i < 8; i++) lwv[i] = lw[i * 64 + j];
  float lbv = lb[j];
  float acc = 0.f;
  int p = start;
  for (; p + 8 <= end; p += 8) {
    // 8 src ids via two broadcast uvec4 loads -> SGPRs
    const uvec4* ip = (const uvec4*)(srcp + p);
    uvec4 I0 = __builtin_nontemporal_load(ip + 0);
    uvec4 I1 = __builtin_nontemporal_load(ip + 1);
    int s0 = __builtin_amdgcn_readfirstlane((int)I0.x);
    int s1 = __builtin_amdgcn_readfirstlane((int)I0.y);
    int s2 = __builtin_amdgcn_readfirstlane((int)I0.z);
    int s3 = __builtin_amdgcn_readfirstlane((int)I0.w);
    int s4 = __builtin_amdgcn_readfirstlane((int)I1.x);
    int s5 = __builtin_amdgcn_readfirstlane((int)I1.y);
    int s6 = __builtin_amdgcn_readfirstlane((int)I1.z);
    int s7 = __builtin_amdgcn_readfirstlane((int)I1.w);
    // 8 edge-attr rows (16B each, broadcast) -> SGPR components
    const uvec4* ep = (const uvec4*)(eapb + (size_t)p * 8);
    uint ua[8][4];
#pragma unroll
    for (int i = 0; i < 8; i++) {
      uvec4 E = __builtin_nontemporal_load(ep + i);
      ua[i][0] = __builtin_amdgcn_readfirstlane(E.x);
      ua[i][1] = __builtin_amdgcn_readfirstlane(E.y);
      ua[i][2] = __builtin_amdgcn_readfirstlane(E.z);
      ua[i][3] = __builtin_amdgcn_readfirstlane(E.w);
    }
    acc += edge8_msg(hinb, s0, j, ua[0][0], ua[0][1], ua[0][2], ua[0][3], lwv, lbv);
    acc += edge8_msg(hinb, s1, j, ua[1][0], ua[1][1], ua[1][2], ua[1][3], lwv, lbv);
    acc += edge8_msg(hinb, s2, j, ua[2][0], ua[2][1], ua[2][2], ua[2][3], lwv, lbv);
    acc += edge8_msg(hinb, s3, j, ua[3][0], ua[3][1], ua[3][2], ua[3][3], lwv, lbv);
    acc += edge8_msg(hinb, s4, j, ua[4][0], ua[4][1], ua[4][2], ua[4][3], lwv, lbv);
    acc += edge8_msg(hinb, s5, j, ua[5][0], ua[5][1], ua[5][2], ua[5][3], lwv, lbv);
    acc += edge8_msg(hinb, s6, j, ua[6][0], ua[6][1], ua[6][2], ua[6][3], lwv, lbv);
    acc += edge8_msg(hinb, s7, j, ua[7][0], ua[7][1], ua[7][2], ua[7][3], lwv, lbv);
  }
  for (; p < end; p++) {
    int s = __builtin_amdgcn_readfirstlane(srcp[p]);
    uvec4 E = __builtin_nontemporal_load((const uvec4*)(eapb + (size_t)p * 8));
    uint e0 = __builtin_amdgcn_readfirstlane(E.x);
    uint e1 = __builtin_amdgcn_readfirstlane(E.y);
    uint e2 = __builtin_amdgcn_readfirstlane(E.z);
    uint e3 = __builtin_amdgcn_readfirstlane(E.w);
    acc += edge8_msg(hinb, s, j, e0, e1, e2, e3, lwv, lbv);
  }
  float hv = __builtin_nontemporal_load(&hinf[(size_t)n * 64 + j]);
  float t = hv + acc;
  float q1 = b1[j];
  for (int k = 0; k < 64; k++) q1 = fmaf(__shfl(t, k), w1[k * 64 + j], q1);
  q1 = fmaxf(q1, 0.f);
  float h2 = b2[j];
  for (int k = 0; k < 64; k++) h2 = fmaf(__shfl(q1, k), w2[k * 64 + j], h2);
  h2 = fmaxf(h2, 0.f);
  float v = lane_layernorm(h2 + hv, lng[j], lnb[j]);
  if (houtf) houtf[(size_t)n * 64 + j] = v;
  houtbf[(size_t)n * 64 + j] = f2bf(v);
}

// ---------------------------------------------------------------------------
// Prep: dec_w1 (264x64, K zero-padded to 288) and dec_w2 (64x32) into per-lane
// bf16 B-fragments for mfma_f32_16x16x32_bf16.
__global__ __launch_bounds__(256) void prep_kernel(
    const float* __restrict__ w1, const float* __restrict__ w2,
    ushort* __restrict__ w1f, ushort* __restrict__ w2f) {
  int t = blockIdx.x * 256 + threadIdx.x;
  if (t < 18432) {
    int j = t & 7, lane = (t >> 3) & 63, f = t >> 9;
    int k = (f >> 2) * 32 + ((lane >> 4) * 8) + j;
    int n = (f & 3) * 16 + (lane & 15);
    float v = (k < 264) ? w1[k * 64 + n] : 0.f;
    w1f[t] = f2bf(v);
  } else {
    int t2 = t - 18432;
    int j = t2 & 7, lane = (t2 >> 3) & 63, f = t2 >> 9;
    int k = (f >> 1) * 32 + ((lane >> 4) * 8) + j;
    int n = (f & 1) * 16 + (lane & 15);
    w2f[t2] = f2bf(w2[k * 32 + n]);
  }
}

// ---------------------------------------------------------------------------
// MFMA decoder, CSR-ordered, M=32 per wave (R13 best: B-frags shared by two
// 16-row A-tiles). 128-thread blocks, 34.8KB LDS, no spills.
#define ZS 272
#define YS 72
#define NGRP 31250
#define NBLK 15625
#define BPX 1954

__global__ __launch_bounds__(128, 2) void decoder_kernel(
    const ushort* __restrict__ hb,
    const int* __restrict__ srcp, const int* __restrict__ dstp,
    const ushort* __restrict__ eapb,
    const ushort* __restrict__ w1f, const ushort* __restrict__ w2f,
    const float* __restrict__ b1, const float* __restrict__ b2,
    const float* __restrict__ w3, const float* __restrict__ b3,
    float* __restrict__ tmp) {
  __shared__ ushort zbuf[2][32 * ZS];
  const int w = threadIdx.x >> 6, l = threadIdx.x & 63;
  const int sub = l & 15, quad = l >> 4;
  int bb = (blockIdx.x & 7) * BPX + (blockIdx.x >> 3);
  if (bb >= NBLK) return;
  const int g = bb * 2 + w;
  ushort* Z = zbuf[w];
  ushort* Y = Z;

  int s32 = __builtin_nontemporal_load(&srcp[g * 32 + (l & 31)]);
  int d32 = __builtin_nontemporal_load(&dstp[g * 32 + (l & 31)]);
  uvec2 pa[8], pb[8];
#pragma unroll
  for (int i = 0; i < 8; i++) {
    int e = 4 * i + quad;
    int s = __shfl(s32, e), d = __shfl(d32, e);
    pa[i] = *(const uvec2*)&hb[(size_t)s * 64 + sub * 4];
    pb[i] = *(const uvec2*)&hb[(size_t)d * 64 + sub * 4];
  }
  uvec2 pe = __builtin_nontemporal_load((const uvec2*)eapb + (size_t)g * 64 + l);

  float b1v[4];
#pragma unroll
  for (int t = 0; t < 4; t++) b1v[t] = b1[t * 16 + sub];
  float b2v0 = b2[sub], b2v1 = b2[16 + sub];
  float w3v0 = w3[sub], w3v1 = w3[16 + sub];
  float b3v = b3[0];

#pragma unroll
  for (int i = 0; i < 8; i++) {
    int e = 4 * i + quad;
    uvec2 a = pa[i], b = pb[i];
    *(uvec2*)&Z[e * ZS + sub * 4] = a;
    *(uvec2*)&Z[e * ZS + 64 + sub * 4] = b;
    float a0 = bflo(a.x), a1 = bfhi(a.x), a2 = bflo(a.y), a3 = bfhi(a.y);
    float c0 = bflo(b.x), c1 = bfhi(b.x), c2 = bflo(b.y), c3 = bfhi(b.y);
    uvec2 u;
    u.x = pkbf(fabsf(a0 - c0), fabsf(a1 - c1));
    u.y = pkbf(fabsf(a2 - c2), fabsf(a3 - c3));
    *(uvec2*)&Z[e * ZS + 128 + sub * 4] = u;
    u.x = pkbf(a0 * c0, a1 * c1);
    u.y = pkbf(a2 * c2, a3 * c3);
    *(uvec2*)&Z[e * ZS + 192 + sub * 4] = u;
  }
  *(uvec2*)&Z[(l >> 1) * ZS + 256 + (l & 1) * 4] = pe;

  f32x4 acc[2][4];
#pragma unroll
  for (int m = 0; m < 2; m++)
#pragma unroll
    for (int t = 0; t < 4; t++) acc[m][t] = (f32x4){0.f, 0.f, 0.f, 0.f};
#pragma unroll
  for (int s = 0; s < 8; s++) {
    bf16x8 afA = *(const bf16x8*)&Z[sub * ZS + s * 32 + quad * 8];
    bf16x8 afB = *(const bf16x8*)&Z[(16 + sub) * ZS + s * 32 + quad * 8];
#pragma unroll
    for (int t = 0; t < 4; t++) {
      bf16x8 bf = ((const bf16x8*)w1f)[(s * 4 + t) * 64 + l];
      acc[0][t] = __builtin_amdgcn_mfma_f32_16x16x32_bf16(afA, bf, acc[0][t], 0, 0, 0);
      acc[1][t] = __builtin_amdgcn_mfma_f32_16x16x32_bf16(afB, bf, acc[1][t], 0, 0, 0);
    }
  }
  {
    bf16x8 afA = (bf16x8){0, 0, 0, 0, 0, 0, 0, 0};
    bf16x8 afB = (bf16x8){0, 0, 0, 0, 0, 0, 0, 0};
    if (quad == 0) {
      afA = *(const bf16x8*)&Z[sub * ZS + 256];
      afB = *(const bf16x8*)&Z[(16 + sub) * ZS + 256];
    }
#pragma unroll
    for (int t = 0; t < 4; t++) {
      bf16x8 bf = ((const bf16x8*)w1f)[(32 + t) * 64 + l];
      acc[0][t] = __builtin_amdgcn_mfma_f32_16x16x32_bf16(afA, bf, acc[0][t], 0, 0, 0);
      acc[1][t] = __builtin_amdgcn_mfma_f32_16x16x32_bf16(afB, bf, acc[1][t], 0, 0, 0);
    }
  }
#pragma unroll
  for (int m = 0; m < 2; m++)
#pragma unroll
    for (int t = 0; t < 4; t++)
#pragma unroll
      for (int r = 0; r < 4; r++)
        Y[(m * 16 + quad * 4 + r) * YS + t * 16 + sub] =
            f2bf(fmaxf(acc[m][t][r] + b1v[t], 0.f));

  bf16x8 w2frag[4];
#pragma unroll
  for (int f = 0; f < 4; f++) w2frag[f] = ((const bf16x8*)w2f)[f * 64 + l];
  f32x4 acc2[2][2];
#pragma unroll
  for (int m = 0; m < 2; m++) {
    acc2[m][0] = (f32x4){0.f, 0.f, 0.f, 0.f};
    acc2[m][1] = (f32x4){0.f, 0.f, 0.f, 0.f};
#pragma unroll
    for (int ks = 0; ks < 2; ks++) {
      union { bf16x8 v; ushort4 u[2]; } ya;
      int o = (m * 16 + sub) * YS + ks * 32 + quad * 8;
      ya.u[0] = *(const ushort4*)&Y[o];
      ya.u[1] = *(const ushort4*)&Y[o + 4];
      acc2[m][0] = __builtin_amdgcn_mfma_f32_16x16x32_bf16(ya.v, w2frag[ks * 2 + 0],
                                                           acc2[m][0], 0, 0, 0);
      acc2[m][1] = __builtin_amdgcn_mfma_f32_16x16x32_bf16(ya.v, w2frag[ks * 2 + 1],
                                                           acc2[m][1], 0, 0, 0);
    }
  }
#pragma unroll
  for (int m = 0; m < 2; m++)
#pragma unroll
    for (int r = 0; r < 4; r++) {
      float o = fmaxf(acc2[m][0][r] + b2v0, 0.f) * w3v0 +
                fmaxf(acc2[m][1][r] + b2v1, 0.f) * w3v1;
      o += __shfl_xor(o, 1);
      o += __shfl_xor(o, 2);
      o += __shfl_xor(o, 4);
      o += __shfl_xor(o, 8);
      if (sub == 0) tmp[g * 32 + m * 16 + quad * 4 + r] = o + b3v;
    }
}

// ---------------------------------------------------------------------------
extern "C" void kernel_launch(void* const* d_in, const int* in_sizes, int n_in,
                              void* d_out, int out_size, void* d_ws, size_t ws_size,
                              hipStream_t stream) {
  const float* x = (const float*)d_in[0];
  const int* ei = (const int*)d_in[1];
  const float* ea = (const float*)d_in[2];
  const float* l0_lin_w = (const float*)d_in[3];
  const float* l0_lin_b = (const float*)d_in[4];
  const float* l0_w1 = (const float*)d_in[5];
  const float* l0_b1 = (const float*)d_in[6];
  const float* l0_w2 = (const float*)d_in[7];
  const float* l0_b2 = (const float*)d_in[8];
  const float* l0_ln_g = (const float*)d_in[9];
  const float* l0_ln_b = (const float*)d_in[10];
  const float* l0_res_w = (const float*)d_in[11];
  const float* l0_res_b = (const float*)d_in[12];
  const float* dec_w1 = (const float*)d_in[29];
  const float* dec_b1 = (const float*)d_in[30];
  const float* dec_w2 = (const float*)d_in[31];
  const float* dec_b2 = (const float*)d_in[32];
  const float* dec_w3 = (const float*)d_in[33];
  const float* dec_b3 = (const float*)d_in[34];

  float* h_a = (float*)d_ws;                      // NN*64 f32
  float* h_b = h_a + (size_t)NN * 64;             // NN*64 f32
  ushort* hbA = (ushort*)(h_b + (size_t)NN * 64); // NN*64 bf16
  ushort* hbB = hbA + (size_t)NN * 64;            // NN*64 bf16
  int* ipos = (int*)(hbB + (size_t)NN * 64);      // NE
  int* srcp = ipos + NE;                          // NE
  int* dstp = srcp + NE;                          // NE
  float* tmp = (float*)(dstp + NE);               // NE f32 (sorted decoder out)
  int* off = (int*)(tmp + NE);                    // NN+1
  int* cnt = off + (NN + 1);                      // NN
  int* bsum = cnt + NN;                           // 256
  ushort* w1f = (ushort*)(bsum + 256);            // 18432 bf16
  ushort* w2f = w1f + 18432;                      // 2048 bf16
  ushort* eapb = w2f + 2048;                      // NE*8 bf16

  const int EB = (NE + 255) / 256;                // 3907
  const int SB = (NN + 256) / 256;                // 196

  // ---- CSR build ----
  hipMemsetAsync(cnt, 0, (size_t)NN * sizeof(int), stream);
  hist_kernel<<<EB, 256, 0, stream>>>(ei, cnt);
  scan1_kernel<<<SB, 256, 0, stream>>>(cnt, off, bsum);
  scan2_kernel<<<1, 256, 0, stream>>>(bsum, SB);
  scan3_kernel<<<SB, 256, 0, stream>>>(off, bsum, cnt);
  scatter_kernel<<<EB, 256, 0, stream>>>(ei, ea, off, cnt, ipos, srcp, dstp, eapb);

  // ---- fused GNN layers ----
  layer0_fused<<<NN / 4, 256, 0, stream>>>(x, h_a, hbA, eapb, srcp, off,
                                           l0_lin_w, l0_lin_b, l0_w1, l0_b1,
                                           l0_w2, l0_b2, l0_ln_g, l0_ln_b,
                                           l0_res_w, l0_res_b);
  layer_fused<<<NN / 4, 256, 0, stream>>>(hbA, h_a, h_b, hbB, eapb, srcp, off,
                                          (const float*)d_in[13], (const float*)d_in[14],
                                          (const float*)d_in[15], (const float*)d_in[16],
                                          (const float*)d_in[17], (const float*)d_in[18],
                                          (const float*)d_in[19], (const float*)d_in[20]);
  layer_fused<<<NN / 4, 256, 0, stream>>>(hbB, h_b, (float*)nullptr, hbA, eapb, srcp, off,
                                          (const float*)d_in[21], (const float*)d_in[22],
                                          (const float*)d_in[23], (const float*)d_in[24],
                                          (const float*)d_in[25], (const float*)d_in[26],
                                          (const float*)d_in[27], (const float*)d_in[28]);

  // ---- decoder ----
  prep_kernel<<<80, 256, 0, stream>>>(dec_w1, dec_w2, w1f, w2f);
  decoder_kernel<<<8 * BPX, 128, 0, stream>>>(hbA, srcp, dstp, eapb,
                                              w1f, w2f, dec_b1, dec_b2,
                                              dec_w3, dec_b3, tmp);
  unperm_kernel<<<EB, 256, 0, stream>>>(tmp, ipos, (float*)d_out);
}